// Round 12
// baseline (331.190 us; speedup 1.0000x reference)
//
#include <hip/hip_runtime.h>

typedef float floatx4 __attribute__((ext_vector_type(4)));
typedef short shortx8 __attribute__((ext_vector_type(8)));

#define E_DIM 1024
#define F_DIM 4096
#define BATCH 4
#define SEQ 1024
#define NH 16
#define HD 64
#define MROWS (BATCH*SEQ)   // 4096
#define QKV_N (3*E_DIM)     // 3072

typedef const __attribute__((address_space(1))) unsigned int* gas_ptr;
typedef __attribute__((address_space(3))) unsigned int* las_ptr;

__device__ __forceinline__ unsigned short f2bf(float f) {
    union { float f; unsigned u; } un; un.f = f;
    unsigned u = un.u;
    u += 0x7fffu + ((u >> 16) & 1u);   // RNE
    return (unsigned short)(u >> 16);
}

// tanh-form GELU, division via v_rcp_f32 (1 inst, ~1 ulp)
__device__ __forceinline__ float gelu_fast(float v) {
    float u = 0.7978845608f * (v + 0.044715f * v * v * v);
    float t = __builtin_exp2f(-2.885390082f * u);   // 2*log2(e)*u
    return v * __builtin_amdgcn_rcpf(1.0f + t);
}

// XCD-aware tile remap, m-fastest within XCD.
__device__ __forceinline__ void xcd_remap(int& m_idx, int& n_idx) {
    int nt = gridDim.x;
    int mt_x = gridDim.y >> 3;
    int lin = blockIdx.y * nt + blockIdx.x;
    int xcd = lin & 7, loc = lin >> 3;
    int n = loc / mt_x;
    int m_local = loc - n * mt_x;
    m_idx = xcd * mt_x + m_local;
    n_idx = n;
}

// ---------------- fused fp32 -> bf16 convert of all 4 weight tensors ----------------
#define S_QKV (3*E_DIM*E_DIM)          // 3145728
#define S_WO  (E_DIM*E_DIM)            // 1048576
#define S_W1  (F_DIM*E_DIM)            // 4194304
#define S_TOT (S_QKV + S_WO + 2*S_W1)  // 12582912
__global__ __launch_bounds__(256) void f2b_all(
        const float* __restrict__ qkv_w, const float* __restrict__ out_w,
        const float* __restrict__ fc1_w, const float* __restrict__ fc2_w,
        unsigned short* __restrict__ wq, unsigned short* __restrict__ wo,
        unsigned short* __restrict__ w1, unsigned short* __restrict__ w2) {
    long idx = ((long)blockIdx.x * 256 + threadIdx.x) * 4;
    const float* src; unsigned short* dst; long off;
    if (idx < S_QKV)                    { src = qkv_w; dst = wq; off = idx; }
    else if (idx < S_QKV + S_WO)        { src = out_w; dst = wo; off = idx - S_QKV; }
    else if (idx < S_QKV + S_WO + S_W1) { src = fc1_w; dst = w1; off = idx - S_QKV - S_WO; }
    else                                { src = fc2_w; dst = w2; off = idx - S_QKV - S_WO - S_W1; }
    float4 v = *(const float4*)&src[off];
    ushort4 o;
    o.x = f2bf(v.x); o.y = f2bf(v.y); o.z = f2bf(v.z); o.w = f2bf(v.w);
    *(ushort4*)&dst[off] = o;
}

// ---------------- LayerNorm (row=1024), fp32 in, bf16 out ----------------
__global__ __launch_bounds__(256) void ln_kernel(const float* __restrict__ x,
                                                 const float* __restrict__ w,
                                                 const float* __restrict__ b,
                                                 unsigned short* __restrict__ out) {
    int row = blockIdx.x;
    const float* xr = x + (size_t)row * E_DIM;
    float v[4];
    float s = 0.f, ss = 0.f;
    for (int i = 0; i < 4; ++i) {
        v[i] = xr[threadIdx.x + i * 256];
        s += v[i]; ss += v[i] * v[i];
    }
    for (int m = 32; m; m >>= 1) { s += __shfl_xor(s, m); ss += __shfl_xor(ss, m); }
    __shared__ float red[8];
    int wave = threadIdx.x >> 6;
    if ((threadIdx.x & 63) == 0) { red[wave] = s; red[wave + 4] = ss; }
    __syncthreads();
    s = red[0] + red[1] + red[2] + red[3];
    ss = red[4] + red[5] + red[6] + red[7];
    float mu = s * (1.0f / E_DIM);
    float var = ss * (1.0f / E_DIM) - mu * mu;
    float rs = rsqrtf(var + 1e-5f);
    for (int i = 0; i < 4; ++i) {
        int c = threadIdx.x + i * 256;
        out[(size_t)row * E_DIM + c] = f2bf((v[i] - mu) * rs * w[c] + b[c]);
    }
}

#define BK 64

// ---------------- GEMM 256x256, 1024 threads = 16 waves (4m x 4n of 64x64).
// Intensity 32 (16 ds_read_b128 + 32 MFMA per wave per K-step), 4 waves/SIMD,
// 1 block/CU, LDS 128 KiB. 2-buf, counted vmcnt(4). (R8 win) ----------------
template<int EPI>
__global__ __launch_bounds__(1024) void gemm_16w(
        const unsigned short* __restrict__ A, const unsigned short* __restrict__ Bw,
        const float* __restrict__ bias, const float* __restrict__ resid,
        float* __restrict__ Cf, unsigned short* __restrict__ Cb,
        int M, int N, int K) {
    __shared__ unsigned short sA[2][256 * BK];   // 32 KB / buf
    __shared__ unsigned short sB[2][256 * BK];   // 32 KB / buf
    int tid = threadIdx.x;
    int wave = tid >> 6, lane = tid & 63;
    int m_idx, n_idx; xcd_remap(m_idx, n_idx);
    int m0 = m_idx * 256, n0 = n_idx * 256;
    int wm = (wave >> 2) * 64, wn = (wave & 3) * 64;
    int l15 = lane & 15, quad = lane >> 4;

    // staging: 1024 threads, 8 threads/row -> 128 rows/round, 2 rounds per operand
    int srow = tid >> 3;                     // 0..127
    int scg  = (tid & 7) ^ (srow & 7);       // pre-swizzled global k-group
    const unsigned short* Ag = A  + (size_t)(m0 + srow) * K + scg * 8;
    const unsigned short* Bg = Bw + (size_t)(n0 + srow) * K + scg * 8;

    floatx4 acc[4][4];
#pragma unroll
    for (int i = 0; i < 4; ++i)
#pragma unroll
        for (int j = 0; j < 4; ++j) acc[i][j] = (floatx4)0.f;

    auto stage = [&](int kt, int bsel) {
        int k0 = kt * BK;
#pragma unroll
        for (int p = 0; p < 2; ++p) {
            __builtin_amdgcn_global_load_lds((gas_ptr)(Ag + k0 + (size_t)p * 128 * K),
                (las_ptr)&sA[bsel][(p * 128 + wave * 8) * BK], 16, 0, 0);
            __builtin_amdgcn_global_load_lds((gas_ptr)(Bg + k0 + (size_t)p * 128 * K),
                (las_ptr)&sB[bsel][(p * 128 + wave * 8) * BK], 16, 0, 0);
        }
    };

    int T = K / BK;   // 16 for K=1024
    stage(0, 0);
    stage(1, 1);
    for (int i = 0; i < T; ++i) {
        if (i + 1 < T) { asm volatile("s_waitcnt vmcnt(4)" ::: "memory"); }
        else           { asm volatile("s_waitcnt vmcnt(0)" ::: "memory"); }
        __builtin_amdgcn_s_barrier();
        int bs = i & 1;
#pragma unroll
        for (int kk8 = 0; kk8 < 8; kk8 += 4) {
            shortx8 af[4], bfr[4];
#pragma unroll
            for (int ii = 0; ii < 4; ++ii) {
                int R = wm + ii * 16 + l15;
                int sc = (quad + kk8) ^ (R & 7);
                af[ii] = *(const shortx8*)&sA[bs][(R * 8 + sc) * 8];
            }
#pragma unroll
            for (int j = 0; j < 4; ++j) {
                int R = wn + j * 16 + l15;
                int sc = (quad + kk8) ^ (R & 7);
                bfr[j] = *(const shortx8*)&sB[bs][(R * 8 + sc) * 8];
            }
#pragma unroll
            for (int ii = 0; ii < 4; ++ii)
#pragma unroll
                for (int j = 0; j < 4; ++j)
                    acc[ii][j] = __builtin_amdgcn_mfma_f32_16x16x32_bf16(af[ii], bfr[j], acc[ii][j], 0, 0, 0);
        }
        __builtin_amdgcn_s_barrier();
        if (i + 2 < T) stage(i + 2, bs);
    }

#pragma unroll
    for (int i = 0; i < 4; ++i) {
        int row = m0 + wm + i * 16 + quad * 4;
#pragma unroll
        for (int j = 0; j < 4; ++j) {
            int col = n0 + wn + j * 16 + l15;
            float bs2 = bias[col];
#pragma unroll
            for (int r = 0; r < 4; ++r) {
                float v = acc[i][j][r] + bs2;
                int rr = row + r;
                if (EPI & 1) v = gelu_fast(v);
                if (EPI & 2) v += resid[(size_t)rr * N + col];
                if (EPI & 4) Cf[(size_t)rr * N + col] = v;
                if (EPI & 8) Cb[(size_t)rr * N + col] = f2bf(v);
            }
        }
    }
}

// ---------------- GEMM 128x128 with in-block K-split (for N=1024 GEMMs).
// 16 waves: (mi,ni,kq); each wave owns a 64x64 sub-tile, consumes k-quarter kq
// of each BK=128 step (8 ds_read + 16 MFMA = intensity-2 optimum), 4 waves/SIMD.
// End: LDS tree-reduction over kq. (R9 win) ----------------
template<int EPI>
__global__ __launch_bounds__(1024) void gemm_ksp(
        const unsigned short* __restrict__ A, const unsigned short* __restrict__ Bw,
        const float* __restrict__ bias, const float* __restrict__ resid,
        float* __restrict__ Cf, unsigned short* __restrict__ Cb,
        int M, int N, int K) {
    __shared__ unsigned short smem[2][2][128 * 128];   // [buf][op] 128 KB total
    int tid = threadIdx.x;
    int wave = tid >> 6, lane = tid & 63;
    int m_idx, n_idx; xcd_remap(m_idx, n_idx);
    int m0 = m_idx * 128, n0 = n_idx * 128;
    int kq = wave & 3, mi = (wave >> 2) & 1, ni = wave >> 3;
    int l15 = lane & 15, quad = lane >> 4;
    int kh = kq >> 1, cb = (kq & 1) * 4;    // k-half + chunk base for this wave

    int lu = wave * 8 + (lane >> 3);        // staging unit within round, 0..127

    floatx4 acc[4][4];
#pragma unroll
    for (int i = 0; i < 4; ++i)
#pragma unroll
        for (int j = 0; j < 4; ++j) acc[i][j] = (floatx4)0.f;

    auto stage = [&](int kt, int b) {
#pragma unroll
        for (int p = 0; p < 2; ++p) {
            int u = p * 128 + lu;
            int row = u >> 1, uh = u & 1;
            int scg = (lane & 7) ^ (row & 7);
            __builtin_amdgcn_global_load_lds(
                (gas_ptr)(A + (size_t)(m0 + row) * K + kt * 128 + uh * 64 + scg * 8),
                (las_ptr)&smem[b][0][(p * 128 + wave * 8) * 64], 16, 0, 0);
        }
#pragma unroll
        for (int p = 0; p < 2; ++p) {
            int u = p * 128 + lu;
            int row = u >> 1, uh = u & 1;
            int scg = (lane & 7) ^ (row & 7);
            __builtin_amdgcn_global_load_lds(
                (gas_ptr)(Bw + (size_t)(n0 + row) * K + kt * 128 + uh * 64 + scg * 8),
                (las_ptr)&smem[b][1][(p * 128 + wave * 8) * 64], 16, 0, 0);
        }
    };

    int T = K / 128;   // 32 (FC2) or 8 (out-proj)
    stage(0, 0);
    stage(1, 1);
    for (int i = 0; i < T; ++i) {
        if (i + 1 < T) { asm volatile("s_waitcnt vmcnt(4)" ::: "memory"); }
        else           { asm volatile("s_waitcnt vmcnt(0)" ::: "memory"); }
        __builtin_amdgcn_s_barrier();
        int bs = i & 1;
        shortx8 af[4], bfr[4];
#pragma unroll
        for (int ii = 0; ii < 4; ++ii) {
            int R = mi * 64 + ii * 16 + l15;
            int sc = (cb + quad) ^ (R & 7);
            af[ii] = *(const shortx8*)&smem[bs][0][((R * 2 + kh) * 8 + sc) * 8];
        }
#pragma unroll
        for (int j = 0; j < 4; ++j) {
            int R = ni * 64 + j * 16 + l15;
            int sc = (cb + quad) ^ (R & 7);
            bfr[j] = *(const shortx8*)&smem[bs][1][((R * 2 + kh) * 8 + sc) * 8];
        }
#pragma unroll
        for (int ii = 0; ii < 4; ++ii)
#pragma unroll
            for (int j = 0; j < 4; ++j)
                acc[ii][j] = __builtin_amdgcn_mfma_f32_16x16x32_bf16(af[ii], bfr[j], acc[ii][j], 0, 0, 0);
        __builtin_amdgcn_s_barrier();
        if (i + 2 < T) stage(i + 2, bs);
    }

    // ---- cross-wave kq reduction through (reused) staging LDS ----
    float* red = (float*)&smem[0][0][0];    // 32768 floats = 128 KB
    int base = (mi * 2 + ni) * 2;
    auto wracc = [&](int rid) {
#pragma unroll
        for (int i2 = 0; i2 < 4; ++i2)
#pragma unroll
            for (int j2 = 0; j2 < 4; ++j2)
                *(floatx4*)&red[(size_t)rid * 4096 + ((i2 * 4 + j2) * 64 + lane) * 4] = acc[i2][j2];
    };
    auto rdacc = [&](int rid) {
#pragma unroll
        for (int i2 = 0; i2 < 4; ++i2)
#pragma unroll
            for (int j2 = 0; j2 < 4; ++j2) {
                floatx4 v = *(const floatx4*)&red[(size_t)rid * 4096 + ((i2 * 4 + j2) * 64 + lane) * 4];
                acc[i2][j2] += v;
            }
    };
    if (kq >= 2) wracc(base + (kq - 2));
    __syncthreads();
    if (kq < 2) rdacc(base + kq);           // kq0 += kq2 ; kq1 += kq3
    __syncthreads();
    if (kq == 1) wracc(base);
    __syncthreads();
    if (kq == 0) {
        rdacc(base);                        // kq0 += (kq1+kq3)
#pragma unroll
        for (int i = 0; i < 4; ++i) {
            int row = m0 + mi * 64 + i * 16 + quad * 4;
#pragma unroll
            for (int j = 0; j < 4; ++j) {
                int col = n0 + ni * 64 + j * 16 + l15;
                float bs2 = bias[col];
#pragma unroll
                for (int r = 0; r < 4; ++r) {
                    float v = acc[i][j][r] + bs2;
                    int rr = row + r;
                    if (EPI & 1) v = gelu_fast(v);
                    if (EPI & 2) v += resid[(size_t)rr * N + col];
                    if (EPI & 4) Cf[(size_t)rr * N + col] = v;
                    if (EPI & 8) Cb[(size_t)rr * N + col] = f2bf(v);
                }
            }
        }
    }
}

// ---------------- V transpose: qkv[.,2048+h*64+d] -> vT[bh][d][t] ----------------
__global__ __launch_bounds__(256) void vtrans_kernel(const unsigned short* __restrict__ qkv,
                                                     unsigned short* __restrict__ vT) {
    __shared__ unsigned short tile[64 * 72];
    int tid = threadIdx.x;
    int bh = blockIdx.y, b = bh >> 4, h = bh & 15;
    int t0 = blockIdx.x * 64;
    const unsigned short* vsrc = qkv + (size_t)b * SEQ * QKV_N + 2 * E_DIM + h * HD;
#pragma unroll
    for (int p = 0; p < 2; ++p) {
        int idx = p * 256 + tid;
        int row = idx >> 3, col = (idx & 7) * 8;
        *(shortx8*)&tile[row * 72 + col] =
            *(const shortx8*)&vsrc[(size_t)(t0 + row) * QKV_N + col];
    }
    __syncthreads();
    int d = tid >> 2, tch = (tid & 3) * 16;
    unsigned short* dst = vT + (size_t)bh * HD * SEQ + (size_t)d * SEQ + t0 + tch;
    shortx8 a0, a1;
#pragma unroll
    for (int j = 0; j < 8; ++j) a0[j] = (short)tile[(tch + j) * 72 + d];
#pragma unroll
    for (int j = 0; j < 8; ++j) a1[j] = (short)tile[(tch + 8 + j) * 72 + d];
    *(shortx8*)&dst[0] = a0;
    *(shortx8*)&dst[8] = a1;
}

// ---------------- Flash attention: NO K/V STAGING, NO BARRIERS.
// K+V per (b,h) = 256 KB; ~8 concurrent bh per XCD = 2 MB, L2-fits (4 MB).
// So K and V fragments load DIRECTLY from global (same 16B/lane pattern as Q):
//   kb0 = K[s0+ct*16+l15][quad*8],   kb1 = +32
//   vb0 = vT[d*16+l15][s0+quad*8],   vb1 = +32
// This removes the per-tile vmcnt(0)+barrier lockstep that R10/R11 proved is
// the limiter (occupancy doubled, VALUBusy fell). Every wave is now fully
// independent: 8 waves/block, waves 0-3 own tile bx, waves 4-7 own 15-bx
// (uniform 68 wave-tile units per block -> perfect CU-level balance; intra-CU
// drift absorbed by the scheduler since nothing synchronizes). ps is
// wave-private LDS scratch (16 KB). Grid 8x64 = 512 blocks, 16 waves/CU. ----------------
__global__ __launch_bounds__(512) void attn_kernel(
        const unsigned short* __restrict__ qkv, const unsigned short* __restrict__ vT,
        unsigned short* __restrict__ out) {
    __shared__ unsigned short ps[8][16 * 64];
    int tid = threadIdx.x;
    int wave = tid >> 6, lane = tid & 63, l15 = lane & 15, quad = lane >> 4;
    int bh = blockIdx.y, b = bh >> 4, h = bh & 15;
    const unsigned short* qbase = qkv + (size_t)b * SEQ * QKV_N + h * HD;
    const unsigned short* kbase = qbase + E_DIM;
    const unsigned short* vtb = vT + (size_t)bh * HD * SEQ;
    const float scale = 0.125f * 1.44269504f;

    int grp = wave >> 2, wv = wave & 3;
    int qt = grp ? (15 - blockIdx.x) : blockIdx.x;
    int qrow = qt * 64 + wv * 16;
    int ntile = qt + 1;

    shortx8 qa0 = *(const shortx8*)&qbase[(size_t)(qrow + l15) * QKV_N + quad * 8];
    shortx8 qa1 = *(const shortx8*)&qbase[(size_t)(qrow + l15) * QKV_N + 32 + quad * 8];

    floatx4 o[4];
    for (int d = 0; d < 4; ++d) o[d] = (floatx4)0.f;
    float mrun[4], lrun[4];
    for (int r = 0; r < 4; ++r) { mrun[r] = -1e30f; lrun[r] = 0.f; }

    for (int t = 0; t < ntile; ++t) {
        int s0 = t * 64;

        floatx4 sfr[4];
#pragma unroll
        for (int ct = 0; ct < 4; ++ct) {
            int R = s0 + ct * 16 + l15;
            shortx8 kb0 = *(const shortx8*)&kbase[(size_t)R * QKV_N + quad * 8];
            shortx8 kb1 = *(const shortx8*)&kbase[(size_t)R * QKV_N + 32 + quad * 8];
            floatx4 s4 = (floatx4)0.f;
            s4 = __builtin_amdgcn_mfma_f32_16x16x32_bf16(qa0, kb0, s4, 0, 0, 0);
            s4 = __builtin_amdgcn_mfma_f32_16x16x32_bf16(qa1, kb1, s4, 0, 0, 0);
            sfr[ct] = s4;
        }

        bool masked = (t == ntile - 1);
#pragma unroll
        for (int r = 0; r < 4; ++r) {
            int qg = qrow + quad * 4 + r;
            float sv[4];
            float mx = mrun[r];
#pragma unroll
            for (int ct = 0; ct < 4; ++ct) {
                float v = sfr[ct][r] * scale;
                if (masked && (s0 + ct * 16 + l15 > qg)) v = -1e30f;
                sv[ct] = v;
                mx = fmaxf(mx, v);
            }
            for (int mm = 8; mm; mm >>= 1) mx = fmaxf(mx, __shfl_xor(mx, mm));
            float alpha = exp2f(mrun[r] - mx);
            mrun[r] = mx;
            float sum = 0.f;
            float pv[4];
#pragma unroll
            for (int ct = 0; ct < 4; ++ct) { pv[ct] = exp2f(sv[ct] - mx); sum += pv[ct]; }
            for (int mm = 8; mm; mm >>= 1) sum += __shfl_xor(sum, mm);
            lrun[r] = lrun[r] * alpha + sum;
#pragma unroll
            for (int d = 0; d < 4; ++d) o[d][r] *= alpha;
            int row = quad * 4 + r;
#pragma unroll
            for (int ct = 0; ct < 4; ++ct) {
                int g = ct * 2 + (l15 >> 3);
                int sc = g ^ (row & 7);
                ps[wave][row * 64 + sc * 8 + (l15 & 7)] = f2bf(pv[ct]);
            }
        }
        shortx8 pa0, pa1;
        {
            int sc0 = quad ^ (l15 & 7), sc1 = (4 + quad) ^ (l15 & 7);
            pa0 = *(const shortx8*)&ps[wave][(l15 * 8 + sc0) * 8];
            pa1 = *(const shortx8*)&ps[wave][(l15 * 8 + sc1) * 8];
        }
#pragma unroll
        for (int d = 0; d < 4; ++d) {
            int R = d * 16 + l15;
            shortx8 vb0 = *(const shortx8*)&vtb[(size_t)R * SEQ + s0 + quad * 8];
            shortx8 vb1 = *(const shortx8*)&vtb[(size_t)R * SEQ + s0 + 32 + quad * 8];
            o[d] = __builtin_amdgcn_mfma_f32_16x16x32_bf16(pa0, vb0, o[d], 0, 0, 0);
            o[d] = __builtin_amdgcn_mfma_f32_16x16x32_bf16(pa1, vb1, o[d], 0, 0, 0);
        }
    }

#pragma unroll
    for (int r = 0; r < 4; ++r) {
        float inv = 1.0f / lrun[r];
        int m = (b << 10) + qrow + quad * 4 + r;
#pragma unroll
        for (int d = 0; d < 4; ++d)
            out[(size_t)m * E_DIM + h * HD + d * 16 + l15] = f2bf(o[d][r] * inv);
    }
}

// ---------------- launch ----------------
extern "C" void kernel_launch(void* const* d_in, const int* in_sizes, int n_in,
                              void* d_out, int out_size, void* d_ws, size_t ws_size,
                              hipStream_t stream) {
    const float* x     = (const float*)d_in[0];
    const float* ln1_w = (const float*)d_in[1];
    const float* ln1_b = (const float*)d_in[2];
    const float* ln2_w = (const float*)d_in[3];
    const float* ln2_b = (const float*)d_in[4];
    const float* qkv_w = (const float*)d_in[5];
    const float* qkv_b = (const float*)d_in[6];
    const float* out_w = (const float*)d_in[7];
    const float* out_b = (const float*)d_in[8];
    const float* fc1_w = (const float*)d_in[9];
    const float* fc1_b = (const float*)d_in[10];
    const float* fc2_w = (const float*)d_in[11];
    const float* fc2_b = (const float*)d_in[12];

    char* ws = (char*)d_ws;
    size_t off = 0;
    auto alloc = [&](size_t bytes) { char* p = ws + off; off += bytes; return p; };
    unsigned short* wq   = (unsigned short*)alloc((size_t)3 * E_DIM * E_DIM * 2);
    unsigned short* wo   = (unsigned short*)alloc((size_t)E_DIM * E_DIM * 2);
    unsigned short* w1   = (unsigned short*)alloc((size_t)F_DIM * E_DIM * 2);
    unsigned short* w2   = (unsigned short*)alloc((size_t)E_DIM * F_DIM * 2);
    unsigned short* h1   = (unsigned short*)alloc((size_t)MROWS * E_DIM * 2);
    unsigned short* qkvb = (unsigned short*)alloc((size_t)MROWS * QKV_N * 2);
    unsigned short* vT   = (unsigned short*)alloc((size_t)BATCH * NH * HD * SEQ * 2);
    unsigned short* attn = (unsigned short*)alloc((size_t)MROWS * E_DIM * 2);
    float*          x1   = (float*)alloc((size_t)MROWS * E_DIM * 4);
    unsigned short* h2   = (unsigned short*)alloc((size_t)MROWS * E_DIM * 2);
    unsigned short* g    = (unsigned short*)alloc((size_t)MROWS * F_DIM * 2);

    // fused weight conversion (12.58M elems, float4 -> ushort4)
    f2b_all<<<S_TOT / 4 / 256, 256, 0, stream>>>(qkv_w, out_w, fc1_w, fc2_w, wq, wo, w1, w2);

    ln_kernel<<<MROWS, 256, 0, stream>>>(x, ln1_w, ln1_b, h1);
    // QKV: 256x256, 16 waves (grid 12x16 = 192 blocks, 1024 threads)
    gemm_16w<8><<<dim3(QKV_N / 256, MROWS / 256), 1024, 0, stream>>>(
        h1, wq, qkv_b, nullptr, nullptr, qkvb, MROWS, QKV_N, E_DIM);
    vtrans_kernel<<<dim3(SEQ / 64, BATCH * NH), 256, 0, stream>>>(qkvb, vT);
    // attn: barrier-free, K/V direct from L2; paired tiles via independent waves
    attn_kernel<<<dim3(8, BATCH * NH), 512, 0, stream>>>(qkvb, vT, attn);
    // out proj + residual(x) -> x1 fp32   (128x128 K-split tiles, 256 blocks, 1/CU)
    gemm_ksp<2 | 4><<<dim3(E_DIM / 128, MROWS / 128), 1024, 0, stream>>>(
        attn, wo, out_b, x, x1, nullptr, MROWS, E_DIM, E_DIM);
    ln_kernel<<<MROWS, 256, 0, stream>>>(x1, ln2_w, ln2_b, h2);
    // FC1: 256x256, 16 waves (grid 16x16 = 256 blocks = 1/CU, 1024 threads)
    gemm_16w<1 | 8><<<dim3(F_DIM / 256, MROWS / 256), 1024, 0, stream>>>(
        h2, w1, fc1_b, nullptr, nullptr, g, MROWS, F_DIM, E_DIM);
    // FC2 + residual(x1) -> d_out fp32   (128x128 K-split tiles, 256 blocks, 1/CU)
    gemm_ksp<2 | 4><<<dim3(E_DIM / 128, MROWS / 128), 1024, 0, stream>>>(
        g, w2, fc2_b, x1, (float*)d_out, nullptr, MROWS, E_DIM, F_DIM);
}

// Round 13
// 314.148 us; speedup vs baseline: 1.0542x; 1.0542x over previous
//
#include <hip/hip_runtime.h>

typedef float floatx4 __attribute__((ext_vector_type(4)));
typedef short shortx8 __attribute__((ext_vector_type(8)));

#define E_DIM 1024
#define F_DIM 4096
#define BATCH 4
#define SEQ 1024
#define NH 16
#define HD 64
#define MROWS (BATCH*SEQ)   // 4096
#define QKV_N (3*E_DIM)     // 3072

typedef const __attribute__((address_space(1))) unsigned int* gas_ptr;
typedef __attribute__((address_space(3))) unsigned int* las_ptr;

__device__ __forceinline__ unsigned short f2bf(float f) {
    union { float f; unsigned u; } un; un.f = f;
    unsigned u = un.u;
    u += 0x7fffu + ((u >> 16) & 1u);   // RNE
    return (unsigned short)(u >> 16);
}

// tanh-form GELU, division via v_rcp_f32 (1 inst, ~1 ulp)
__device__ __forceinline__ float gelu_fast(float v) {
    float u = 0.7978845608f * (v + 0.044715f * v * v * v);
    float t = __builtin_exp2f(-2.885390082f * u);   // 2*log2(e)*u
    return v * __builtin_amdgcn_rcpf(1.0f + t);
}

// XCD-aware tile remap, m-fastest within XCD.
__device__ __forceinline__ void xcd_remap(int& m_idx, int& n_idx) {
    int nt = gridDim.x;
    int mt_x = gridDim.y >> 3;
    int lin = blockIdx.y * nt + blockIdx.x;
    int xcd = lin & 7, loc = lin >> 3;
    int n = loc / mt_x;
    int m_local = loc - n * mt_x;
    m_idx = xcd * mt_x + m_local;
    n_idx = n;
}

// ---------------- fused fp32 -> bf16 convert of all 4 weight tensors ----------------
#define S_QKV (3*E_DIM*E_DIM)          // 3145728
#define S_WO  (E_DIM*E_DIM)            // 1048576
#define S_W1  (F_DIM*E_DIM)            // 4194304
#define S_TOT (S_QKV + S_WO + 2*S_W1)  // 12582912
__global__ __launch_bounds__(256) void f2b_all(
        const float* __restrict__ qkv_w, const float* __restrict__ out_w,
        const float* __restrict__ fc1_w, const float* __restrict__ fc2_w,
        unsigned short* __restrict__ wq, unsigned short* __restrict__ wo,
        unsigned short* __restrict__ w1, unsigned short* __restrict__ w2) {
    long idx = ((long)blockIdx.x * 256 + threadIdx.x) * 4;
    const float* src; unsigned short* dst; long off;
    if (idx < S_QKV)                    { src = qkv_w; dst = wq; off = idx; }
    else if (idx < S_QKV + S_WO)        { src = out_w; dst = wo; off = idx - S_QKV; }
    else if (idx < S_QKV + S_WO + S_W1) { src = fc1_w; dst = w1; off = idx - S_QKV - S_WO; }
    else                                { src = fc2_w; dst = w2; off = idx - S_QKV - S_WO - S_W1; }
    float4 v = *(const float4*)&src[off];
    ushort4 o;
    o.x = f2bf(v.x); o.y = f2bf(v.y); o.z = f2bf(v.z); o.w = f2bf(v.w);
    *(ushort4*)&dst[off] = o;
}

// ---------------- LayerNorm (row=1024), fp32 in, bf16 out ----------------
__global__ __launch_bounds__(256) void ln_kernel(const float* __restrict__ x,
                                                 const float* __restrict__ w,
                                                 const float* __restrict__ b,
                                                 unsigned short* __restrict__ out) {
    int row = blockIdx.x;
    const float* xr = x + (size_t)row * E_DIM;
    float v[4];
    float s = 0.f, ss = 0.f;
    for (int i = 0; i < 4; ++i) {
        v[i] = xr[threadIdx.x + i * 256];
        s += v[i]; ss += v[i] * v[i];
    }
    for (int m = 32; m; m >>= 1) { s += __shfl_xor(s, m); ss += __shfl_xor(ss, m); }
    __shared__ float red[8];
    int wave = threadIdx.x >> 6;
    if ((threadIdx.x & 63) == 0) { red[wave] = s; red[wave + 4] = ss; }
    __syncthreads();
    s = red[0] + red[1] + red[2] + red[3];
    ss = red[4] + red[5] + red[6] + red[7];
    float mu = s * (1.0f / E_DIM);
    float var = ss * (1.0f / E_DIM) - mu * mu;
    float rs = rsqrtf(var + 1e-5f);
    for (int i = 0; i < 4; ++i) {
        int c = threadIdx.x + i * 256;
        out[(size_t)row * E_DIM + c] = f2bf((v[i] - mu) * rs * w[c] + b[c]);
    }
}

#define BK 64

// ---------------- GEMM 256x256, 1024 threads = 16 waves (4m x 4n of 64x64).
// Intensity 32 (16 ds_read_b128 + 32 MFMA per wave per K-step), 4 waves/SIMD,
// 1 block/CU, LDS 128 KiB. 2-buf, counted vmcnt(4). (R8 win) ----------------
template<int EPI>
__global__ __launch_bounds__(1024) void gemm_16w(
        const unsigned short* __restrict__ A, const unsigned short* __restrict__ Bw,
        const float* __restrict__ bias, const float* __restrict__ resid,
        float* __restrict__ Cf, unsigned short* __restrict__ Cb,
        int M, int N, int K) {
    __shared__ unsigned short sA[2][256 * BK];   // 32 KB / buf
    __shared__ unsigned short sB[2][256 * BK];   // 32 KB / buf
    int tid = threadIdx.x;
    int wave = tid >> 6, lane = tid & 63;
    int m_idx, n_idx; xcd_remap(m_idx, n_idx);
    int m0 = m_idx * 256, n0 = n_idx * 256;
    int wm = (wave >> 2) * 64, wn = (wave & 3) * 64;
    int l15 = lane & 15, quad = lane >> 4;

    // staging: 1024 threads, 8 threads/row -> 128 rows/round, 2 rounds per operand
    int srow = tid >> 3;                     // 0..127
    int scg  = (tid & 7) ^ (srow & 7);       // pre-swizzled global k-group
    const unsigned short* Ag = A  + (size_t)(m0 + srow) * K + scg * 8;
    const unsigned short* Bg = Bw + (size_t)(n0 + srow) * K + scg * 8;

    floatx4 acc[4][4];
#pragma unroll
    for (int i = 0; i < 4; ++i)
#pragma unroll
        for (int j = 0; j < 4; ++j) acc[i][j] = (floatx4)0.f;

    auto stage = [&](int kt, int bsel) {
        int k0 = kt * BK;
#pragma unroll
        for (int p = 0; p < 2; ++p) {
            __builtin_amdgcn_global_load_lds((gas_ptr)(Ag + k0 + (size_t)p * 128 * K),
                (las_ptr)&sA[bsel][(p * 128 + wave * 8) * BK], 16, 0, 0);
            __builtin_amdgcn_global_load_lds((gas_ptr)(Bg + k0 + (size_t)p * 128 * K),
                (las_ptr)&sB[bsel][(p * 128 + wave * 8) * BK], 16, 0, 0);
        }
    };

    int T = K / BK;   // 16 for K=1024
    stage(0, 0);
    stage(1, 1);
    for (int i = 0; i < T; ++i) {
        if (i + 1 < T) { asm volatile("s_waitcnt vmcnt(4)" ::: "memory"); }
        else           { asm volatile("s_waitcnt vmcnt(0)" ::: "memory"); }
        __builtin_amdgcn_s_barrier();
        int bs = i & 1;
#pragma unroll
        for (int kk8 = 0; kk8 < 8; kk8 += 4) {
            shortx8 af[4], bfr[4];
#pragma unroll
            for (int ii = 0; ii < 4; ++ii) {
                int R = wm + ii * 16 + l15;
                int sc = (quad + kk8) ^ (R & 7);
                af[ii] = *(const shortx8*)&sA[bs][(R * 8 + sc) * 8];
            }
#pragma unroll
            for (int j = 0; j < 4; ++j) {
                int R = wn + j * 16 + l15;
                int sc = (quad + kk8) ^ (R & 7);
                bfr[j] = *(const shortx8*)&sB[bs][(R * 8 + sc) * 8];
            }
#pragma unroll
            for (int ii = 0; ii < 4; ++ii)
#pragma unroll
                for (int j = 0; j < 4; ++j)
                    acc[ii][j] = __builtin_amdgcn_mfma_f32_16x16x32_bf16(af[ii], bfr[j], acc[ii][j], 0, 0, 0);
        }
        __builtin_amdgcn_s_barrier();
        if (i + 2 < T) stage(i + 2, bs);
    }

#pragma unroll
    for (int i = 0; i < 4; ++i) {
        int row = m0 + wm + i * 16 + quad * 4;
#pragma unroll
        for (int j = 0; j < 4; ++j) {
            int col = n0 + wn + j * 16 + l15;
            float bs2 = bias[col];
#pragma unroll
            for (int r = 0; r < 4; ++r) {
                float v = acc[i][j][r] + bs2;
                int rr = row + r;
                if (EPI & 1) v = gelu_fast(v);
                if (EPI & 2) v += resid[(size_t)rr * N + col];
                if (EPI & 4) Cf[(size_t)rr * N + col] = v;
                if (EPI & 8) Cb[(size_t)rr * N + col] = f2bf(v);
            }
        }
    }
}

// ---------------- GEMM 128x128 with in-block K-split (for N=1024 GEMMs).
// 16 waves: (mi,ni,kq); each wave owns a 64x64 sub-tile, consumes k-quarter kq
// of each BK=128 step (8 ds_read + 16 MFMA = intensity-2 optimum), 4 waves/SIMD.
// End: LDS tree-reduction over kq. (R9 win) ----------------
template<int EPI>
__global__ __launch_bounds__(1024) void gemm_ksp(
        const unsigned short* __restrict__ A, const unsigned short* __restrict__ Bw,
        const float* __restrict__ bias, const float* __restrict__ resid,
        float* __restrict__ Cf, unsigned short* __restrict__ Cb,
        int M, int N, int K) {
    __shared__ unsigned short smem[2][2][128 * 128];   // [buf][op] 128 KB total
    int tid = threadIdx.x;
    int wave = tid >> 6, lane = tid & 63;
    int m_idx, n_idx; xcd_remap(m_idx, n_idx);
    int m0 = m_idx * 128, n0 = n_idx * 128;
    int kq = wave & 3, mi = (wave >> 2) & 1, ni = wave >> 3;
    int l15 = lane & 15, quad = lane >> 4;
    int kh = kq >> 1, cb = (kq & 1) * 4;    // k-half + chunk base for this wave

    int lu = wave * 8 + (lane >> 3);        // staging unit within round, 0..127

    floatx4 acc[4][4];
#pragma unroll
    for (int i = 0; i < 4; ++i)
#pragma unroll
        for (int j = 0; j < 4; ++j) acc[i][j] = (floatx4)0.f;

    auto stage = [&](int kt, int b) {
#pragma unroll
        for (int p = 0; p < 2; ++p) {
            int u = p * 128 + lu;
            int row = u >> 1, uh = u & 1;
            int scg = (lane & 7) ^ (row & 7);
            __builtin_amdgcn_global_load_lds(
                (gas_ptr)(A + (size_t)(m0 + row) * K + kt * 128 + uh * 64 + scg * 8),
                (las_ptr)&smem[b][0][(p * 128 + wave * 8) * 64], 16, 0, 0);
        }
#pragma unroll
        for (int p = 0; p < 2; ++p) {
            int u = p * 128 + lu;
            int row = u >> 1, uh = u & 1;
            int scg = (lane & 7) ^ (row & 7);
            __builtin_amdgcn_global_load_lds(
                (gas_ptr)(Bw + (size_t)(n0 + row) * K + kt * 128 + uh * 64 + scg * 8),
                (las_ptr)&smem[b][1][(p * 128 + wave * 8) * 64], 16, 0, 0);
        }
    };

    int T = K / 128;   // 32 (FC2) or 8 (out-proj)
    stage(0, 0);
    stage(1, 1);
    for (int i = 0; i < T; ++i) {
        if (i + 1 < T) { asm volatile("s_waitcnt vmcnt(4)" ::: "memory"); }
        else           { asm volatile("s_waitcnt vmcnt(0)" ::: "memory"); }
        __builtin_amdgcn_s_barrier();
        int bs = i & 1;
        shortx8 af[4], bfr[4];
#pragma unroll
        for (int ii = 0; ii < 4; ++ii) {
            int R = mi * 64 + ii * 16 + l15;
            int sc = (cb + quad) ^ (R & 7);
            af[ii] = *(const shortx8*)&smem[bs][0][((R * 2 + kh) * 8 + sc) * 8];
        }
#pragma unroll
        for (int j = 0; j < 4; ++j) {
            int R = ni * 64 + j * 16 + l15;
            int sc = (cb + quad) ^ (R & 7);
            bfr[j] = *(const shortx8*)&smem[bs][1][((R * 2 + kh) * 8 + sc) * 8];
        }
#pragma unroll
        for (int ii = 0; ii < 4; ++ii)
#pragma unroll
            for (int j = 0; j < 4; ++j)
                acc[ii][j] = __builtin_amdgcn_mfma_f32_16x16x32_bf16(af[ii], bfr[j], acc[ii][j], 0, 0, 0);
        __builtin_amdgcn_s_barrier();
        if (i + 2 < T) stage(i + 2, bs);
    }

    // ---- cross-wave kq reduction through (reused) staging LDS ----
    float* red = (float*)&smem[0][0][0];    // 32768 floats = 128 KB
    int base = (mi * 2 + ni) * 2;
    auto wracc = [&](int rid) {
#pragma unroll
        for (int i2 = 0; i2 < 4; ++i2)
#pragma unroll
            for (int j2 = 0; j2 < 4; ++j2)
                *(floatx4*)&red[(size_t)rid * 4096 + ((i2 * 4 + j2) * 64 + lane) * 4] = acc[i2][j2];
    };
    auto rdacc = [&](int rid) {
#pragma unroll
        for (int i2 = 0; i2 < 4; ++i2)
#pragma unroll
            for (int j2 = 0; j2 < 4; ++j2) {
                floatx4 v = *(const floatx4*)&red[(size_t)rid * 4096 + ((i2 * 4 + j2) * 64 + lane) * 4];
                acc[i2][j2] += v;
            }
    };
    if (kq >= 2) wracc(base + (kq - 2));
    __syncthreads();
    if (kq < 2) rdacc(base + kq);           // kq0 += kq2 ; kq1 += kq3
    __syncthreads();
    if (kq == 1) wracc(base);
    __syncthreads();
    if (kq == 0) {
        rdacc(base);                        // kq0 += (kq1+kq3)
#pragma unroll
        for (int i = 0; i < 4; ++i) {
            int row = m0 + mi * 64 + i * 16 + quad * 4;
#pragma unroll
            for (int j = 0; j < 4; ++j) {
                int col = n0 + ni * 64 + j * 16 + l15;
                float bs2 = bias[col];
#pragma unroll
                for (int r = 0; r < 4; ++r) {
                    float v = acc[i][j][r] + bs2;
                    int rr = row + r;
                    if (EPI & 1) v = gelu_fast(v);
                    if (EPI & 2) v += resid[(size_t)rr * N + col];
                    if (EPI & 4) Cf[(size_t)rr * N + col] = v;
                    if (EPI & 8) Cb[(size_t)rr * N + col] = f2bf(v);
                }
            }
        }
    }
}

// ---------------- V transpose: qkv[.,2048+h*64+d] -> vT[bh][d][t] ----------------
__global__ __launch_bounds__(256) void vtrans_kernel(const unsigned short* __restrict__ qkv,
                                                     unsigned short* __restrict__ vT) {
    __shared__ unsigned short tile[64 * 72];
    int tid = threadIdx.x;
    int bh = blockIdx.y, b = bh >> 4, h = bh & 15;
    int t0 = blockIdx.x * 64;
    const unsigned short* vsrc = qkv + (size_t)b * SEQ * QKV_N + 2 * E_DIM + h * HD;
#pragma unroll
    for (int p = 0; p < 2; ++p) {
        int idx = p * 256 + tid;
        int row = idx >> 3, col = (idx & 7) * 8;
        *(shortx8*)&tile[row * 72 + col] =
            *(const shortx8*)&vsrc[(size_t)(t0 + row) * QKV_N + col];
    }
    __syncthreads();
    int d = tid >> 2, tch = (tid & 3) * 16;
    unsigned short* dst = vT + (size_t)bh * HD * SEQ + (size_t)d * SEQ + t0 + tch;
    shortx8 a0, a1;
#pragma unroll
    for (int j = 0; j < 8; ++j) a0[j] = (short)tile[(tch + j) * 72 + d];
#pragma unroll
    for (int j = 0; j < 8; ++j) a1[j] = (short)tile[(tch + 8 + j) * 72 + d];
    *(shortx8*)&dst[0] = a0;
    *(shortx8*)&dst[8] = a1;
}

// ---------------- Flash attention (R9 structure, PROVEN 49.5us): 64-key tiles,
// paired q-tiles (2-pass), 4 waves, double-buffered K/V staging with prefetch
// under compute. R10-R12 structural variants all regressed (tail imbalance /
// lockstep / exposed L2 latency). Added: T13 defer-max (skip O-rescale when the
// tile max doesn't exceed running max by >8 in log2 domain; P bounded by 2^8,
// fine in bf16; shortens the alpha->PV dependency chain). ----------------
__global__ __launch_bounds__(256) void attn_kernel(
        const unsigned short* __restrict__ qkv, const unsigned short* __restrict__ vT,
        unsigned short* __restrict__ out) {
    __shared__ unsigned short kt[2][64 * 64];
    __shared__ unsigned short vt[2][64 * 64];
    __shared__ unsigned short ps[4][16 * 64];
    int tid = threadIdx.x;
    int wave = tid >> 6, lane = tid & 63, l15 = lane & 15, quad = lane >> 4;
    int bh = blockIdx.y, b = bh >> 4, h = bh & 15;
    const unsigned short* qbase = qkv + (size_t)b * SEQ * QKV_N + h * HD;
    const unsigned short* kbase = qbase + E_DIM;
    const unsigned short* vtb = vT + (size_t)bh * HD * SEQ;

    int srl = lane >> 3;
    int scg = (lane & 7) ^ srl;

    const float scale = 0.125f * 1.44269504f;

    auto stage = [&](int t, int bsel) {
        int s0 = t * 64;
#pragma unroll
        for (int p = 0; p < 2; ++p) {
            int rbase = p * 32 + wave * 8;
            __builtin_amdgcn_global_load_lds(
                (gas_ptr)&kbase[(size_t)(s0 + rbase + srl) * QKV_N + scg * 8],
                (las_ptr)&kt[bsel][rbase * 64], 16, 0, 0);
            __builtin_amdgcn_global_load_lds(
                (gas_ptr)&vtb[(size_t)(rbase + srl) * SEQ + s0 + scg * 8],
                (las_ptr)&vt[bsel][rbase * 64], 16, 0, 0);
        }
    };

    for (int pass = 0; pass < 2; ++pass) {
        int qt = (pass == 0) ? blockIdx.x : (15 - blockIdx.x);
        int q0 = qt * 64;
        int qrow = q0 + wave * 16;

        shortx8 qa0 = *(const shortx8*)&qbase[(size_t)(qrow + l15) * QKV_N + quad * 8];
        shortx8 qa1 = *(const shortx8*)&qbase[(size_t)(qrow + l15) * QKV_N + 32 + quad * 8];

        floatx4 o[4];
        for (int d = 0; d < 4; ++d) o[d] = (floatx4)0.f;
        float mrun[4], lrun[4];
        for (int r = 0; r < 4; ++r) { mrun[r] = -1e30f; lrun[r] = 0.f; }

        int ntile = qt + 1;
        __syncthreads();          // prior pass's buf reads done before re-staging buf0
        stage(0, 0);
        for (int t = 0; t < ntile; ++t) {
            asm volatile("s_waitcnt vmcnt(0)" ::: "memory");   // my stage(t) rows landed
            __builtin_amdgcn_s_barrier();                      // everyone's landed + WAR fence
            if (t + 1 < ntile) stage(t + 1, (t + 1) & 1);      // prefetch under compute
            int bsel = t & 1;
            int s0 = t * 64;

            floatx4 sfr[4];
#pragma unroll
            for (int ct = 0; ct < 4; ++ct) {
                int R = ct * 16 + l15;
                int sc0 = quad ^ (R & 7), sc1 = (4 + quad) ^ (R & 7);
                shortx8 kb0 = *(const shortx8*)&kt[bsel][(R * 8 + sc0) * 8];
                shortx8 kb1 = *(const shortx8*)&kt[bsel][(R * 8 + sc1) * 8];
                floatx4 s4 = (floatx4)0.f;
                s4 = __builtin_amdgcn_mfma_f32_16x16x32_bf16(qa0, kb0, s4, 0, 0, 0);
                s4 = __builtin_amdgcn_mfma_f32_16x16x32_bf16(qa1, kb1, s4, 0, 0, 0);
                sfr[ct] = s4;
            }

            bool masked = (t == ntile - 1);
#pragma unroll
            for (int r = 0; r < 4; ++r) {
                int qg = qrow + quad * 4 + r;
                float sv[4];
                float pmax = -1e30f;
#pragma unroll
                for (int ct = 0; ct < 4; ++ct) {
                    float v = sfr[ct][r] * scale;
                    if (masked && (s0 + ct * 16 + l15 > qg)) v = -1e30f;
                    sv[ct] = v;
                    pmax = fmaxf(pmax, v);
                }
                for (int mm = 8; mm; mm >>= 1) pmax = fmaxf(pmax, __shfl_xor(pmax, mm));
                // T13 defer-max: if no row in the wave grew its max by >8 (log2
                // domain), keep mrun (alpha==1), skip rescale entirely.
                bool defer = __all(pmax - mrun[r] <= 8.0f);
                float mx = defer ? mrun[r] : fmaxf(pmax, mrun[r]);
                if (!defer) {
                    float alpha = exp2f(mrun[r] - mx);
                    mrun[r] = mx;
                    lrun[r] *= alpha;
#pragma unroll
                    for (int d = 0; d < 4; ++d) o[d][r] *= alpha;
                }
                float sum = 0.f;
                float pv[4];
#pragma unroll
                for (int ct = 0; ct < 4; ++ct) { pv[ct] = exp2f(sv[ct] - mx); sum += pv[ct]; }
                for (int mm = 8; mm; mm >>= 1) sum += __shfl_xor(sum, mm);
                lrun[r] += sum;
                int row = quad * 4 + r;
#pragma unroll
                for (int ct = 0; ct < 4; ++ct) {
                    int g = ct * 2 + (l15 >> 3);
                    int sc = g ^ (row & 7);
                    ps[wave][row * 64 + sc * 8 + (l15 & 7)] = f2bf(pv[ct]);
                }
            }
            shortx8 pa0, pa1;
            {
                int sc0 = quad ^ (l15 & 7), sc1 = (4 + quad) ^ (l15 & 7);
                pa0 = *(const shortx8*)&ps[wave][(l15 * 8 + sc0) * 8];
                pa1 = *(const shortx8*)&ps[wave][(l15 * 8 + sc1) * 8];
            }
#pragma unroll
            for (int d = 0; d < 4; ++d) {
                int R = d * 16 + l15;
                int sc0 = quad ^ (R & 7), sc1 = (4 + quad) ^ (R & 7);
                shortx8 vb0 = *(const shortx8*)&vt[bsel][(R * 8 + sc0) * 8];
                shortx8 vb1 = *(const shortx8*)&vt[bsel][(R * 8 + sc1) * 8];
                o[d] = __builtin_amdgcn_mfma_f32_16x16x32_bf16(pa0, vb0, o[d], 0, 0, 0);
                o[d] = __builtin_amdgcn_mfma_f32_16x16x32_bf16(pa1, vb1, o[d], 0, 0, 0);
            }
        }

#pragma unroll
        for (int r = 0; r < 4; ++r) {
            float inv = 1.0f / lrun[r];
            int m = (b << 10) + qrow + quad * 4 + r;
#pragma unroll
            for (int d = 0; d < 4; ++d)
                out[(size_t)m * E_DIM + h * HD + d * 16 + l15] = f2bf(o[d][r] * inv);
        }
    }
}

// ---------------- launch ----------------
extern "C" void kernel_launch(void* const* d_in, const int* in_sizes, int n_in,
                              void* d_out, int out_size, void* d_ws, size_t ws_size,
                              hipStream_t stream) {
    const float* x     = (const float*)d_in[0];
    const float* ln1_w = (const float*)d_in[1];
    const float* ln1_b = (const float*)d_in[2];
    const float* ln2_w = (const float*)d_in[3];
    const float* ln2_b = (const float*)d_in[4];
    const float* qkv_w = (const float*)d_in[5];
    const float* qkv_b = (const float*)d_in[6];
    const float* out_w = (const float*)d_in[7];
    const float* out_b = (const float*)d_in[8];
    const float* fc1_w = (const float*)d_in[9];
    const float* fc1_b = (const float*)d_in[10];
    const float* fc2_w = (const float*)d_in[11];
    const float* fc2_b = (const float*)d_in[12];

    char* ws = (char*)d_ws;
    size_t off = 0;
    auto alloc = [&](size_t bytes) { char* p = ws + off; off += bytes; return p; };
    unsigned short* wq   = (unsigned short*)alloc((size_t)3 * E_DIM * E_DIM * 2);
    unsigned short* wo   = (unsigned short*)alloc((size_t)E_DIM * E_DIM * 2);
    unsigned short* w1   = (unsigned short*)alloc((size_t)F_DIM * E_DIM * 2);
    unsigned short* w2   = (unsigned short*)alloc((size_t)E_DIM * F_DIM * 2);
    unsigned short* h1   = (unsigned short*)alloc((size_t)MROWS * E_DIM * 2);
    unsigned short* qkvb = (unsigned short*)alloc((size_t)MROWS * QKV_N * 2);
    unsigned short* vT   = (unsigned short*)alloc((size_t)BATCH * NH * HD * SEQ * 2);
    unsigned short* attn = (unsigned short*)alloc((size_t)MROWS * E_DIM * 2);
    float*          x1   = (float*)alloc((size_t)MROWS * E_DIM * 4);
    unsigned short* h2   = (unsigned short*)alloc((size_t)MROWS * E_DIM * 2);
    unsigned short* g    = (unsigned short*)alloc((size_t)MROWS * F_DIM * 2);

    // fused weight conversion (12.58M elems, float4 -> ushort4)
    f2b_all<<<S_TOT / 4 / 256, 256, 0, stream>>>(qkv_w, out_w, fc1_w, fc2_w, wq, wo, w1, w2);

    ln_kernel<<<MROWS, 256, 0, stream>>>(x, ln1_w, ln1_b, h1);
    // QKV: 256x256, 16 waves (grid 12x16 = 192 blocks, 1024 threads)
    gemm_16w<8><<<dim3(QKV_N / 256, MROWS / 256), 1024, 0, stream>>>(
        h1, wq, qkv_b, nullptr, nullptr, qkvb, MROWS, QKV_N, E_DIM);
    vtrans_kernel<<<dim3(SEQ / 64, BATCH * NH), 256, 0, stream>>>(qkvb, vT);
    // attn: R9 proven structure (paired 2-pass, dbuf staging) + defer-max
    attn_kernel<<<dim3(8, BATCH * NH), 256, 0, stream>>>(qkvb, vT, attn);
    // out proj + residual(x) -> x1 fp32   (128x128 K-split tiles, 256 blocks, 1/CU)
    gemm_ksp<2 | 4><<<dim3(E_DIM / 128, MROWS / 128), 1024, 0, stream>>>(
        attn, wo, out_b, x, x1, nullptr, MROWS, E_DIM, E_DIM);
    ln_kernel<<<MROWS, 256, 0, stream>>>(x1, ln2_w, ln2_b, h2);
    // FC1: 256x256, 16 waves (grid 16x16 = 256 blocks = 1/CU, 1024 threads)
    gemm_16w<1 | 8><<<dim3(F_DIM / 256, MROWS / 256), 1024, 0, stream>>>(
        h2, w1, fc1_b, nullptr, nullptr, g, MROWS, F_DIM, E_DIM);
    // FC2 + residual(x1) -> d_out fp32   (128x128 K-split tiles, 256 blocks, 1/CU)
    gemm_ksp<2 | 4><<<dim3(E_DIM / 128, MROWS / 128), 1024, 0, stream>>>(
        g, w2, fc2_b, x1, (float*)d_out, nullptr, MROWS, E_DIM, F_DIM);
}

// Round 14
// 311.327 us; speedup vs baseline: 1.0638x; 1.0091x over previous
//
#include <hip/hip_runtime.h>

typedef float floatx4 __attribute__((ext_vector_type(4)));
typedef short shortx8 __attribute__((ext_vector_type(8)));

#define E_DIM 1024
#define F_DIM 4096
#define BATCH 4
#define SEQ 1024
#define NH 16
#define HD 64
#define MROWS (BATCH*SEQ)   // 4096
#define QKV_N (3*E_DIM)     // 3072

typedef const __attribute__((address_space(1))) unsigned int* gas_ptr;
typedef __attribute__((address_space(3))) unsigned int* las_ptr;

__device__ __forceinline__ unsigned short f2bf(float f) {
    union { float f; unsigned u; } un; un.f = f;
    unsigned u = un.u;
    u += 0x7fffu + ((u >> 16) & 1u);   // RNE
    return (unsigned short)(u >> 16);
}

// tanh-form GELU, division via v_rcp_f32 (1 inst, ~1 ulp)
__device__ __forceinline__ float gelu_fast(float v) {
    float u = 0.7978845608f * (v + 0.044715f * v * v * v);
    float t = __builtin_exp2f(-2.885390082f * u);   // 2*log2(e)*u
    return v * __builtin_amdgcn_rcpf(1.0f + t);
}

// XCD-aware tile remap, m-fastest within XCD.
__device__ __forceinline__ void xcd_remap(int& m_idx, int& n_idx) {
    int nt = gridDim.x;
    int mt_x = gridDim.y >> 3;
    int lin = blockIdx.y * nt + blockIdx.x;
    int xcd = lin & 7, loc = lin >> 3;
    int n = loc / mt_x;
    int m_local = loc - n * mt_x;
    m_idx = xcd * mt_x + m_local;
    n_idx = n;
}

// ---------------- fused fp32 -> bf16 convert of all 4 weight tensors ----------------
#define S_QKV (3*E_DIM*E_DIM)          // 3145728
#define S_WO  (E_DIM*E_DIM)            // 1048576
#define S_W1  (F_DIM*E_DIM)            // 4194304
#define S_TOT (S_QKV + S_WO + 2*S_W1)  // 12582912
__global__ __launch_bounds__(256) void f2b_all(
        const float* __restrict__ qkv_w, const float* __restrict__ out_w,
        const float* __restrict__ fc1_w, const float* __restrict__ fc2_w,
        unsigned short* __restrict__ wq, unsigned short* __restrict__ wo,
        unsigned short* __restrict__ w1, unsigned short* __restrict__ w2) {
    long idx = ((long)blockIdx.x * 256 + threadIdx.x) * 4;
    const float* src; unsigned short* dst; long off;
    if (idx < S_QKV)                    { src = qkv_w; dst = wq; off = idx; }
    else if (idx < S_QKV + S_WO)        { src = out_w; dst = wo; off = idx - S_QKV; }
    else if (idx < S_QKV + S_WO + S_W1) { src = fc1_w; dst = w1; off = idx - S_QKV - S_WO; }
    else                                { src = fc2_w; dst = w2; off = idx - S_QKV - S_WO - S_W1; }
    float4 v = *(const float4*)&src[off];
    ushort4 o;
    o.x = f2bf(v.x); o.y = f2bf(v.y); o.z = f2bf(v.z); o.w = f2bf(v.w);
    *(ushort4*)&dst[off] = o;
}

// ---------------- LayerNorm (row=1024), fp32 in, bf16 out ----------------
__global__ __launch_bounds__(256) void ln_kernel(const float* __restrict__ x,
                                                 const float* __restrict__ w,
                                                 const float* __restrict__ b,
                                                 unsigned short* __restrict__ out) {
    int row = blockIdx.x;
    const float* xr = x + (size_t)row * E_DIM;
    float v[4];
    float s = 0.f, ss = 0.f;
    for (int i = 0; i < 4; ++i) {
        v[i] = xr[threadIdx.x + i * 256];
        s += v[i]; ss += v[i] * v[i];
    }
    for (int m = 32; m; m >>= 1) { s += __shfl_xor(s, m); ss += __shfl_xor(ss, m); }
    __shared__ float red[8];
    int wave = threadIdx.x >> 6;
    if ((threadIdx.x & 63) == 0) { red[wave] = s; red[wave + 4] = ss; }
    __syncthreads();
    s = red[0] + red[1] + red[2] + red[3];
    ss = red[4] + red[5] + red[6] + red[7];
    float mu = s * (1.0f / E_DIM);
    float var = ss * (1.0f / E_DIM) - mu * mu;
    float rs = rsqrtf(var + 1e-5f);
    for (int i = 0; i < 4; ++i) {
        int c = threadIdx.x + i * 256;
        out[(size_t)row * E_DIM + c] = f2bf((v[i] - mu) * rs * w[c] + b[c]);
    }
}

#define BK 64

// ---------------- GEMM 256x256, 1024 threads = 16 waves (4m x 4n of 64x64).
// Intensity 32 (16 ds_read_b128 + 32 MFMA per wave per K-step), 4 waves/SIMD,
// 1 block/CU, LDS 128 KiB. 2-buf, counted vmcnt(4). (R8 win)
// EPI bit 16: multiply cols < E_DIM by 0.125*log2e after bias — folds the
// attention softmax scale into Q at the source, removing 16 VALU mults per
// tile per wave from attn's critical softmax chain. ----------------
template<int EPI>
__global__ __launch_bounds__(1024) void gemm_16w(
        const unsigned short* __restrict__ A, const unsigned short* __restrict__ Bw,
        const float* __restrict__ bias, const float* __restrict__ resid,
        float* __restrict__ Cf, unsigned short* __restrict__ Cb,
        int M, int N, int K) {
    __shared__ unsigned short sA[2][256 * BK];   // 32 KB / buf
    __shared__ unsigned short sB[2][256 * BK];   // 32 KB / buf
    int tid = threadIdx.x;
    int wave = tid >> 6, lane = tid & 63;
    int m_idx, n_idx; xcd_remap(m_idx, n_idx);
    int m0 = m_idx * 256, n0 = n_idx * 256;
    int wm = (wave >> 2) * 64, wn = (wave & 3) * 64;
    int l15 = lane & 15, quad = lane >> 4;

    // staging: 1024 threads, 8 threads/row -> 128 rows/round, 2 rounds per operand
    int srow = tid >> 3;                     // 0..127
    int scg  = (tid & 7) ^ (srow & 7);       // pre-swizzled global k-group
    const unsigned short* Ag = A  + (size_t)(m0 + srow) * K + scg * 8;
    const unsigned short* Bg = Bw + (size_t)(n0 + srow) * K + scg * 8;

    floatx4 acc[4][4];
#pragma unroll
    for (int i = 0; i < 4; ++i)
#pragma unroll
        for (int j = 0; j < 4; ++j) acc[i][j] = (floatx4)0.f;

    auto stage = [&](int kt, int bsel) {
        int k0 = kt * BK;
#pragma unroll
        for (int p = 0; p < 2; ++p) {
            __builtin_amdgcn_global_load_lds((gas_ptr)(Ag + k0 + (size_t)p * 128 * K),
                (las_ptr)&sA[bsel][(p * 128 + wave * 8) * BK], 16, 0, 0);
            __builtin_amdgcn_global_load_lds((gas_ptr)(Bg + k0 + (size_t)p * 128 * K),
                (las_ptr)&sB[bsel][(p * 128 + wave * 8) * BK], 16, 0, 0);
        }
    };

    int T = K / BK;   // 16 for K=1024
    stage(0, 0);
    stage(1, 1);
    for (int i = 0; i < T; ++i) {
        if (i + 1 < T) { asm volatile("s_waitcnt vmcnt(4)" ::: "memory"); }
        else           { asm volatile("s_waitcnt vmcnt(0)" ::: "memory"); }
        __builtin_amdgcn_s_barrier();
        int bs = i & 1;
#pragma unroll
        for (int kk8 = 0; kk8 < 8; kk8 += 4) {
            shortx8 af[4], bfr[4];
#pragma unroll
            for (int ii = 0; ii < 4; ++ii) {
                int R = wm + ii * 16 + l15;
                int sc = (quad + kk8) ^ (R & 7);
                af[ii] = *(const shortx8*)&sA[bs][(R * 8 + sc) * 8];
            }
#pragma unroll
            for (int j = 0; j < 4; ++j) {
                int R = wn + j * 16 + l15;
                int sc = (quad + kk8) ^ (R & 7);
                bfr[j] = *(const shortx8*)&sB[bs][(R * 8 + sc) * 8];
            }
#pragma unroll
            for (int ii = 0; ii < 4; ++ii)
#pragma unroll
                for (int j = 0; j < 4; ++j)
                    acc[ii][j] = __builtin_amdgcn_mfma_f32_16x16x32_bf16(af[ii], bfr[j], acc[ii][j], 0, 0, 0);
        }
        __builtin_amdgcn_s_barrier();
        if (i + 2 < T) stage(i + 2, bs);
    }

#pragma unroll
    for (int i = 0; i < 4; ++i) {
        int row = m0 + wm + i * 16 + quad * 4;
#pragma unroll
        for (int j = 0; j < 4; ++j) {
            int col = n0 + wn + j * 16 + l15;
            float bs2 = bias[col];
#pragma unroll
            for (int r = 0; r < 4; ++r) {
                float v = acc[i][j][r] + bs2;
                int rr = row + r;
                if (EPI & 1) v = gelu_fast(v);
                if (EPI & 16) { if (col < E_DIM) v *= 0.18033688f; }  // 0.125*log2e into Q
                if (EPI & 2) v += resid[(size_t)rr * N + col];
                if (EPI & 4) Cf[(size_t)rr * N + col] = v;
                if (EPI & 8) Cb[(size_t)rr * N + col] = f2bf(v);
            }
        }
    }
}

// ---------------- GEMM 128x128 with in-block K-split (for N=1024 GEMMs).
// 16 waves: (mi,ni,kq); each wave owns a 64x64 sub-tile, consumes k-quarter kq
// of each BK=128 step (8 ds_read + 16 MFMA = intensity-2 optimum), 4 waves/SIMD.
// End: LDS tree-reduction over kq. (R9 win) ----------------
template<int EPI>
__global__ __launch_bounds__(1024) void gemm_ksp(
        const unsigned short* __restrict__ A, const unsigned short* __restrict__ Bw,
        const float* __restrict__ bias, const float* __restrict__ resid,
        float* __restrict__ Cf, unsigned short* __restrict__ Cb,
        int M, int N, int K) {
    __shared__ unsigned short smem[2][2][128 * 128];   // [buf][op] 128 KB total
    int tid = threadIdx.x;
    int wave = tid >> 6, lane = tid & 63;
    int m_idx, n_idx; xcd_remap(m_idx, n_idx);
    int m0 = m_idx * 128, n0 = n_idx * 128;
    int kq = wave & 3, mi = (wave >> 2) & 1, ni = wave >> 3;
    int l15 = lane & 15, quad = lane >> 4;
    int kh = kq >> 1, cb = (kq & 1) * 4;    // k-half + chunk base for this wave

    int lu = wave * 8 + (lane >> 3);        // staging unit within round, 0..127

    floatx4 acc[4][4];
#pragma unroll
    for (int i = 0; i < 4; ++i)
#pragma unroll
        for (int j = 0; j < 4; ++j) acc[i][j] = (floatx4)0.f;

    auto stage = [&](int kt, int b) {
#pragma unroll
        for (int p = 0; p < 2; ++p) {
            int u = p * 128 + lu;
            int row = u >> 1, uh = u & 1;
            int scg = (lane & 7) ^ (row & 7);
            __builtin_amdgcn_global_load_lds(
                (gas_ptr)(A + (size_t)(m0 + row) * K + kt * 128 + uh * 64 + scg * 8),
                (las_ptr)&smem[b][0][(p * 128 + wave * 8) * 64], 16, 0, 0);
        }
#pragma unroll
        for (int p = 0; p < 2; ++p) {
            int u = p * 128 + lu;
            int row = u >> 1, uh = u & 1;
            int scg = (lane & 7) ^ (row & 7);
            __builtin_amdgcn_global_load_lds(
                (gas_ptr)(Bw + (size_t)(n0 + row) * K + kt * 128 + uh * 64 + scg * 8),
                (las_ptr)&smem[b][1][(p * 128 + wave * 8) * 64], 16, 0, 0);
        }
    };

    int T = K / 128;   // 32 (FC2) or 8 (out-proj)
    stage(0, 0);
    stage(1, 1);
    for (int i = 0; i < T; ++i) {
        if (i + 1 < T) { asm volatile("s_waitcnt vmcnt(4)" ::: "memory"); }
        else           { asm volatile("s_waitcnt vmcnt(0)" ::: "memory"); }
        __builtin_amdgcn_s_barrier();
        int bs = i & 1;
        shortx8 af[4], bfr[4];
#pragma unroll
        for (int ii = 0; ii < 4; ++ii) {
            int R = mi * 64 + ii * 16 + l15;
            int sc = (cb + quad) ^ (R & 7);
            af[ii] = *(const shortx8*)&smem[bs][0][((R * 2 + kh) * 8 + sc) * 8];
        }
#pragma unroll
        for (int j = 0; j < 4; ++j) {
            int R = ni * 64 + j * 16 + l15;
            int sc = (cb + quad) ^ (R & 7);
            bfr[j] = *(const shortx8*)&smem[bs][1][((R * 2 + kh) * 8 + sc) * 8];
        }
#pragma unroll
        for (int ii = 0; ii < 4; ++ii)
#pragma unroll
            for (int j = 0; j < 4; ++j)
                acc[ii][j] = __builtin_amdgcn_mfma_f32_16x16x32_bf16(af[ii], bfr[j], acc[ii][j], 0, 0, 0);
        __builtin_amdgcn_s_barrier();
        if (i + 2 < T) stage(i + 2, bs);
    }

    // ---- cross-wave kq reduction through (reused) staging LDS ----
    float* red = (float*)&smem[0][0][0];    // 32768 floats = 128 KB
    int base = (mi * 2 + ni) * 2;
    auto wracc = [&](int rid) {
#pragma unroll
        for (int i2 = 0; i2 < 4; ++i2)
#pragma unroll
            for (int j2 = 0; j2 < 4; ++j2)
                *(floatx4*)&red[(size_t)rid * 4096 + ((i2 * 4 + j2) * 64 + lane) * 4] = acc[i2][j2];
    };
    auto rdacc = [&](int rid) {
#pragma unroll
        for (int i2 = 0; i2 < 4; ++i2)
#pragma unroll
            for (int j2 = 0; j2 < 4; ++j2) {
                floatx4 v = *(const floatx4*)&red[(size_t)rid * 4096 + ((i2 * 4 + j2) * 64 + lane) * 4];
                acc[i2][j2] += v;
            }
    };
    if (kq >= 2) wracc(base + (kq - 2));
    __syncthreads();
    if (kq < 2) rdacc(base + kq);           // kq0 += kq2 ; kq1 += kq3
    __syncthreads();
    if (kq == 1) wracc(base);
    __syncthreads();
    if (kq == 0) {
        rdacc(base);                        // kq0 += (kq1+kq3)
#pragma unroll
        for (int i = 0; i < 4; ++i) {
            int row = m0 + mi * 64 + i * 16 + quad * 4;
#pragma unroll
            for (int j = 0; j < 4; ++j) {
                int col = n0 + ni * 64 + j * 16 + l15;
                float bs2 = bias[col];
#pragma unroll
                for (int r = 0; r < 4; ++r) {
                    float v = acc[i][j][r] + bs2;
                    int rr = row + r;
                    if (EPI & 1) v = gelu_fast(v);
                    if (EPI & 2) v += resid[(size_t)rr * N + col];
                    if (EPI & 4) Cf[(size_t)rr * N + col] = v;
                    if (EPI & 8) Cb[(size_t)rr * N + col] = f2bf(v);
                }
            }
        }
    }
}

// ---------------- V transpose: qkv[.,2048+h*64+d] -> vT[bh][d][t] ----------------
__global__ __launch_bounds__(256) void vtrans_kernel(const unsigned short* __restrict__ qkv,
                                                     unsigned short* __restrict__ vT) {
    __shared__ unsigned short tile[64 * 72];
    int tid = threadIdx.x;
    int bh = blockIdx.y, b = bh >> 4, h = bh & 15;
    int t0 = blockIdx.x * 64;
    const unsigned short* vsrc = qkv + (size_t)b * SEQ * QKV_N + 2 * E_DIM + h * HD;
#pragma unroll
    for (int p = 0; p < 2; ++p) {
        int idx = p * 256 + tid;
        int row = idx >> 3, col = (idx & 7) * 8;
        *(shortx8*)&tile[row * 72 + col] =
            *(const shortx8*)&vsrc[(size_t)(t0 + row) * QKV_N + col];
    }
    __syncthreads();
    int d = tid >> 2, tch = (tid & 3) * 16;
    unsigned short* dst = vT + (size_t)bh * HD * SEQ + (size_t)d * SEQ + t0 + tch;
    shortx8 a0, a1;
#pragma unroll
    for (int j = 0; j < 8; ++j) a0[j] = (short)tile[(tch + j) * 72 + d];
#pragma unroll
    for (int j = 0; j < 8; ++j) a1[j] = (short)tile[(tch + 8 + j) * 72 + d];
    *(shortx8*)&dst[0] = a0;
    *(shortx8*)&dst[8] = a1;
}

// ---------------- Flash attention (R9 structure, PROVEN best): 64-key tiles,
// paired q-tiles (2-pass), 4 waves, double-buffered K/V staging with prefetch
// under compute. Scores arrive PRE-SCALED (Q carries 0.125*log2e from the QKV
// epilogue) so the softmax uses sfr directly — no per-tile scale mults.
// R10-R13 variants (1-tile/block, 8-wave lockstep, no-staging, defer-max) all
// regressed or were neutral; do not modify this structure. ----------------
__global__ __launch_bounds__(256) void attn_kernel(
        const unsigned short* __restrict__ qkv, const unsigned short* __restrict__ vT,
        unsigned short* __restrict__ out) {
    __shared__ unsigned short kt[2][64 * 64];
    __shared__ unsigned short vt[2][64 * 64];
    __shared__ unsigned short ps[4][16 * 64];
    int tid = threadIdx.x;
    int wave = tid >> 6, lane = tid & 63, l15 = lane & 15, quad = lane >> 4;
    int bh = blockIdx.y, b = bh >> 4, h = bh & 15;
    const unsigned short* qbase = qkv + (size_t)b * SEQ * QKV_N + h * HD;
    const unsigned short* kbase = qbase + E_DIM;
    const unsigned short* vtb = vT + (size_t)bh * HD * SEQ;

    int srl = lane >> 3;
    int scg = (lane & 7) ^ srl;

    auto stage = [&](int t, int bsel) {
        int s0 = t * 64;
#pragma unroll
        for (int p = 0; p < 2; ++p) {
            int rbase = p * 32 + wave * 8;
            __builtin_amdgcn_global_load_lds(
                (gas_ptr)&kbase[(size_t)(s0 + rbase + srl) * QKV_N + scg * 8],
                (las_ptr)&kt[bsel][rbase * 64], 16, 0, 0);
            __builtin_amdgcn_global_load_lds(
                (gas_ptr)&vtb[(size_t)(rbase + srl) * SEQ + s0 + scg * 8],
                (las_ptr)&vt[bsel][rbase * 64], 16, 0, 0);
        }
    };

    for (int pass = 0; pass < 2; ++pass) {
        int qt = (pass == 0) ? blockIdx.x : (15 - blockIdx.x);
        int q0 = qt * 64;
        int qrow = q0 + wave * 16;

        shortx8 qa0 = *(const shortx8*)&qbase[(size_t)(qrow + l15) * QKV_N + quad * 8];
        shortx8 qa1 = *(const shortx8*)&qbase[(size_t)(qrow + l15) * QKV_N + 32 + quad * 8];

        floatx4 o[4];
        for (int d = 0; d < 4; ++d) o[d] = (floatx4)0.f;
        float mrun[4], lrun[4];
        for (int r = 0; r < 4; ++r) { mrun[r] = -1e30f; lrun[r] = 0.f; }

        int ntile = qt + 1;
        __syncthreads();          // prior pass's buf reads done before re-staging buf0
        stage(0, 0);
        for (int t = 0; t < ntile; ++t) {
            asm volatile("s_waitcnt vmcnt(0)" ::: "memory");   // my stage(t) rows landed
            __builtin_amdgcn_s_barrier();                      // everyone's landed + WAR fence
            if (t + 1 < ntile) stage(t + 1, (t + 1) & 1);      // prefetch under compute
            int bsel = t & 1;
            int s0 = t * 64;

            floatx4 sfr[4];
#pragma unroll
            for (int ct = 0; ct < 4; ++ct) {
                int R = ct * 16 + l15;
                int sc0 = quad ^ (R & 7), sc1 = (4 + quad) ^ (R & 7);
                shortx8 kb0 = *(const shortx8*)&kt[bsel][(R * 8 + sc0) * 8];
                shortx8 kb1 = *(const shortx8*)&kt[bsel][(R * 8 + sc1) * 8];
                floatx4 s4 = (floatx4)0.f;
                s4 = __builtin_amdgcn_mfma_f32_16x16x32_bf16(qa0, kb0, s4, 0, 0, 0);
                s4 = __builtin_amdgcn_mfma_f32_16x16x32_bf16(qa1, kb1, s4, 0, 0, 0);
                sfr[ct] = s4;
            }

            bool masked = (t == ntile - 1);
#pragma unroll
            for (int r = 0; r < 4; ++r) {
                int qg = qrow + quad * 4 + r;
                float sv[4];
                float mx = mrun[r];
#pragma unroll
                for (int ct = 0; ct < 4; ++ct) {
                    float v = sfr[ct][r];               // pre-scaled in QKV epilogue
                    if (masked && (s0 + ct * 16 + l15 > qg)) v = -1e30f;
                    sv[ct] = v;
                    mx = fmaxf(mx, v);
                }
                for (int mm = 8; mm; mm >>= 1) mx = fmaxf(mx, __shfl_xor(mx, mm));
                float alpha = exp2f(mrun[r] - mx);
                mrun[r] = mx;
                float sum = 0.f;
                float pv[4];
#pragma unroll
                for (int ct = 0; ct < 4; ++ct) { pv[ct] = exp2f(sv[ct] - mx); sum += pv[ct]; }
                for (int mm = 8; mm; mm >>= 1) sum += __shfl_xor(sum, mm);
                lrun[r] = lrun[r] * alpha + sum;
#pragma unroll
                for (int d = 0; d < 4; ++d) o[d][r] *= alpha;
                int row = quad * 4 + r;
#pragma unroll
                for (int ct = 0; ct < 4; ++ct) {
                    int g = ct * 2 + (l15 >> 3);
                    int sc = g ^ (row & 7);
                    ps[wave][row * 64 + sc * 8 + (l15 & 7)] = f2bf(pv[ct]);
                }
            }
            shortx8 pa0, pa1;
            {
                int sc0 = quad ^ (l15 & 7), sc1 = (4 + quad) ^ (l15 & 7);
                pa0 = *(const shortx8*)&ps[wave][(l15 * 8 + sc0) * 8];
                pa1 = *(const shortx8*)&ps[wave][(l15 * 8 + sc1) * 8];
            }
#pragma unroll
            for (int d = 0; d < 4; ++d) {
                int R = d * 16 + l15;
                int sc0 = quad ^ (R & 7), sc1 = (4 + quad) ^ (R & 7);
                shortx8 vb0 = *(const shortx8*)&vt[bsel][(R * 8 + sc0) * 8];
                shortx8 vb1 = *(const shortx8*)&vt[bsel][(R * 8 + sc1) * 8];
                o[d] = __builtin_amdgcn_mfma_f32_16x16x32_bf16(pa0, vb0, o[d], 0, 0, 0);
                o[d] = __builtin_amdgcn_mfma_f32_16x16x32_bf16(pa1, vb1, o[d], 0, 0, 0);
            }
        }

#pragma unroll
        for (int r = 0; r < 4; ++r) {
            float inv = 1.0f / lrun[r];
            int m = (b << 10) + qrow + quad * 4 + r;
#pragma unroll
            for (int d = 0; d < 4; ++d)
                out[(size_t)m * E_DIM + h * HD + d * 16 + l15] = f2bf(o[d][r] * inv);
        }
    }
}

// ---------------- launch ----------------
extern "C" void kernel_launch(void* const* d_in, const int* in_sizes, int n_in,
                              void* d_out, int out_size, void* d_ws, size_t ws_size,
                              hipStream_t stream) {
    const float* x     = (const float*)d_in[0];
    const float* ln1_w = (const float*)d_in[1];
    const float* ln1_b = (const float*)d_in[2];
    const float* ln2_w = (const float*)d_in[3];
    const float* ln2_b = (const float*)d_in[4];
    const float* qkv_w = (const float*)d_in[5];
    const float* qkv_b = (const float*)d_in[6];
    const float* out_w = (const float*)d_in[7];
    const float* out_b = (const float*)d_in[8];
    const float* fc1_w = (const float*)d_in[9];
    const float* fc1_b = (const float*)d_in[10];
    const float* fc2_w = (const float*)d_in[11];
    const float* fc2_b = (const float*)d_in[12];

    char* ws = (char*)d_ws;
    size_t off = 0;
    auto alloc = [&](size_t bytes) { char* p = ws + off; off += bytes; return p; };
    unsigned short* wq   = (unsigned short*)alloc((size_t)3 * E_DIM * E_DIM * 2);
    unsigned short* wo   = (unsigned short*)alloc((size_t)E_DIM * E_DIM * 2);
    unsigned short* w1   = (unsigned short*)alloc((size_t)F_DIM * E_DIM * 2);
    unsigned short* w2   = (unsigned short*)alloc((size_t)E_DIM * F_DIM * 2);
    unsigned short* h1   = (unsigned short*)alloc((size_t)MROWS * E_DIM * 2);
    unsigned short* qkvb = (unsigned short*)alloc((size_t)MROWS * QKV_N * 2);
    unsigned short* vT   = (unsigned short*)alloc((size_t)BATCH * NH * HD * SEQ * 2);
    unsigned short* attn = (unsigned short*)alloc((size_t)MROWS * E_DIM * 2);
    float*          x1   = (float*)alloc((size_t)MROWS * E_DIM * 4);
    unsigned short* h2   = (unsigned short*)alloc((size_t)MROWS * E_DIM * 2);
    unsigned short* g    = (unsigned short*)alloc((size_t)MROWS * F_DIM * 2);

    // fused weight conversion (12.58M elems, float4 -> ushort4)
    f2b_all<<<S_TOT / 4 / 256, 256, 0, stream>>>(qkv_w, out_w, fc1_w, fc2_w, wq, wo, w1, w2);

    ln_kernel<<<MROWS, 256, 0, stream>>>(x, ln1_w, ln1_b, h1);
    // QKV: 256x256, 16 waves; EPI 16 pre-scales Q cols by 0.125*log2e
    gemm_16w<8 | 16><<<dim3(QKV_N / 256, MROWS / 256), 1024, 0, stream>>>(
        h1, wq, qkv_b, nullptr, nullptr, qkvb, MROWS, QKV_N, E_DIM);
    vtrans_kernel<<<dim3(SEQ / 64, BATCH * NH), 256, 0, stream>>>(qkvb, vT);
    // attn: R9 proven structure (paired 2-pass, dbuf staging), scale pre-folded
    attn_kernel<<<dim3(8, BATCH * NH), 256, 0, stream>>>(qkvb, vT, attn);
    // out proj + residual(x) -> x1 fp32   (128x128 K-split tiles, 256 blocks, 1/CU)
    gemm_ksp<2 | 4><<<dim3(E_DIM / 128, MROWS / 128), 1024, 0, stream>>>(
        attn, wo, out_b, x, x1, nullptr, MROWS, E_DIM, E_DIM);
    ln_kernel<<<MROWS, 256, 0, stream>>>(x1, ln2_w, ln2_b, h2);
    // FC1: 256x256, 16 waves (grid 16x16 = 256 blocks = 1/CU, 1024 threads)
    gemm_16w<1 | 8><<<dim3(F_DIM / 256, MROWS / 256), 1024, 0, stream>>>(
        h2, w1, fc1_b, nullptr, nullptr, g, MROWS, F_DIM, E_DIM);
    // FC2 + residual(x1) -> d_out fp32   (128x128 K-split tiles, 256 blocks, 1/CU)
    gemm_ksp<2 | 4><<<dim3(E_DIM / 128, MROWS / 128), 1024, 0, stream>>>(
        g, w2, fc2_b, x1, (float*)d_out, nullptr, MROWS, E_DIM, F_DIM);
}

// Round 15
// 306.419 us; speedup vs baseline: 1.0808x; 1.0160x over previous
//
#include <hip/hip_runtime.h>

typedef float floatx4 __attribute__((ext_vector_type(4)));
typedef short shortx8 __attribute__((ext_vector_type(8)));

#define E_DIM 1024
#define F_DIM 4096
#define BATCH 4
#define SEQ 1024
#define NH 16
#define HD 64
#define MROWS (BATCH*SEQ)   // 4096
#define QKV_N (3*E_DIM)     // 3072

typedef const __attribute__((address_space(1))) unsigned int* gas_ptr;
typedef __attribute__((address_space(3))) unsigned int* las_ptr;

__device__ __forceinline__ unsigned short f2bf(float f) {
    union { float f; unsigned u; } un; un.f = f;
    unsigned u = un.u;
    u += 0x7fffu + ((u >> 16) & 1u);   // RNE
    return (unsigned short)(u >> 16);
}

// tanh-form GELU, division via v_rcp_f32 (1 inst, ~1 ulp)
__device__ __forceinline__ float gelu_fast(float v) {
    float u = 0.7978845608f * (v + 0.044715f * v * v * v);
    float t = __builtin_exp2f(-2.885390082f * u);   // 2*log2(e)*u
    return v * __builtin_amdgcn_rcpf(1.0f + t);
}

// XCD-aware tile remap, m-fastest within XCD.
__device__ __forceinline__ void xcd_remap(int& m_idx, int& n_idx) {
    int nt = gridDim.x;
    int mt_x = gridDim.y >> 3;
    int lin = blockIdx.y * nt + blockIdx.x;
    int xcd = lin & 7, loc = lin >> 3;
    int n = loc / mt_x;
    int m_local = loc - n * mt_x;
    m_idx = xcd * mt_x + m_local;
    n_idx = n;
}

// ---------------- fused fp32 -> bf16 convert of all 4 weight tensors ----------------
#define S_QKV (3*E_DIM*E_DIM)          // 3145728
#define S_WO  (E_DIM*E_DIM)            // 1048576
#define S_W1  (F_DIM*E_DIM)            // 4194304
#define S_TOT (S_QKV + S_WO + 2*S_W1)  // 12582912
__global__ __launch_bounds__(256) void f2b_all(
        const float* __restrict__ qkv_w, const float* __restrict__ out_w,
        const float* __restrict__ fc1_w, const float* __restrict__ fc2_w,
        unsigned short* __restrict__ wq, unsigned short* __restrict__ wo,
        unsigned short* __restrict__ w1, unsigned short* __restrict__ w2) {
    long idx = ((long)blockIdx.x * 256 + threadIdx.x) * 4;
    const float* src; unsigned short* dst; long off;
    if (idx < S_QKV)                    { src = qkv_w; dst = wq; off = idx; }
    else if (idx < S_QKV + S_WO)        { src = out_w; dst = wo; off = idx - S_QKV; }
    else if (idx < S_QKV + S_WO + S_W1) { src = fc1_w; dst = w1; off = idx - S_QKV - S_WO; }
    else                                { src = fc2_w; dst = w2; off = idx - S_QKV - S_WO - S_W1; }
    float4 v = *(const float4*)&src[off];
    ushort4 o;
    o.x = f2bf(v.x); o.y = f2bf(v.y); o.z = f2bf(v.z); o.w = f2bf(v.w);
    *(ushort4*)&dst[off] = o;
}

// ---------------- LayerNorm (row=1024), fp32 in, bf16 out ----------------
__global__ __launch_bounds__(256) void ln_kernel(const float* __restrict__ x,
                                                 const float* __restrict__ w,
                                                 const float* __restrict__ b,
                                                 unsigned short* __restrict__ out) {
    int row = blockIdx.x;
    const float* xr = x + (size_t)row * E_DIM;
    float v[4];
    float s = 0.f, ss = 0.f;
    for (int i = 0; i < 4; ++i) {
        v[i] = xr[threadIdx.x + i * 256];
        s += v[i]; ss += v[i] * v[i];
    }
    for (int m = 32; m; m >>= 1) { s += __shfl_xor(s, m); ss += __shfl_xor(ss, m); }
    __shared__ float red[8];
    int wave = threadIdx.x >> 6;
    if ((threadIdx.x & 63) == 0) { red[wave] = s; red[wave + 4] = ss; }
    __syncthreads();
    s = red[0] + red[1] + red[2] + red[3];
    ss = red[4] + red[5] + red[6] + red[7];
    float mu = s * (1.0f / E_DIM);
    float var = ss * (1.0f / E_DIM) - mu * mu;
    float rs = rsqrtf(var + 1e-5f);
    for (int i = 0; i < 4; ++i) {
        int c = threadIdx.x + i * 256;
        out[(size_t)row * E_DIM + c] = f2bf((v[i] - mu) * rs * w[c] + b[c]);
    }
}

#define BK 64

// ---------------- GEMM 256x256, 1024 threads = 16 waves (4m x 4n of 64x64).
// Intensity 32 (16 ds_read_b128 + 32 MFMA per wave per K-step), 4 waves/SIMD,
// 1 block/CU, LDS 128 KiB. 2-buf, counted vmcnt(4). (R8 win)
// EPI bit 16: multiply cols < E_DIM by 0.125*log2e after bias — folds the
// attention softmax scale into Q at the source. ----------------
template<int EPI>
__global__ __launch_bounds__(1024) void gemm_16w(
        const unsigned short* __restrict__ A, const unsigned short* __restrict__ Bw,
        const float* __restrict__ bias, const float* __restrict__ resid,
        float* __restrict__ Cf, unsigned short* __restrict__ Cb,
        int M, int N, int K) {
    __shared__ unsigned short sA[2][256 * BK];   // 32 KB / buf
    __shared__ unsigned short sB[2][256 * BK];   // 32 KB / buf
    int tid = threadIdx.x;
    int wave = tid >> 6, lane = tid & 63;
    int m_idx, n_idx; xcd_remap(m_idx, n_idx);
    int m0 = m_idx * 256, n0 = n_idx * 256;
    int wm = (wave >> 2) * 64, wn = (wave & 3) * 64;
    int l15 = lane & 15, quad = lane >> 4;

    // staging: 1024 threads, 8 threads/row -> 128 rows/round, 2 rounds per operand
    int srow = tid >> 3;                     // 0..127
    int scg  = (tid & 7) ^ (srow & 7);       // pre-swizzled global k-group
    const unsigned short* Ag = A  + (size_t)(m0 + srow) * K + scg * 8;
    const unsigned short* Bg = Bw + (size_t)(n0 + srow) * K + scg * 8;

    floatx4 acc[4][4];
#pragma unroll
    for (int i = 0; i < 4; ++i)
#pragma unroll
        for (int j = 0; j < 4; ++j) acc[i][j] = (floatx4)0.f;

    auto stage = [&](int kt, int bsel) {
        int k0 = kt * BK;
#pragma unroll
        for (int p = 0; p < 2; ++p) {
            __builtin_amdgcn_global_load_lds((gas_ptr)(Ag + k0 + (size_t)p * 128 * K),
                (las_ptr)&sA[bsel][(p * 128 + wave * 8) * BK], 16, 0, 0);
            __builtin_amdgcn_global_load_lds((gas_ptr)(Bg + k0 + (size_t)p * 128 * K),
                (las_ptr)&sB[bsel][(p * 128 + wave * 8) * BK], 16, 0, 0);
        }
    };

    int T = K / BK;   // 16 for K=1024
    stage(0, 0);
    stage(1, 1);
    for (int i = 0; i < T; ++i) {
        if (i + 1 < T) { asm volatile("s_waitcnt vmcnt(4)" ::: "memory"); }
        else           { asm volatile("s_waitcnt vmcnt(0)" ::: "memory"); }
        __builtin_amdgcn_s_barrier();
        int bs = i & 1;
#pragma unroll
        for (int kk8 = 0; kk8 < 8; kk8 += 4) {
            shortx8 af[4], bfr[4];
#pragma unroll
            for (int ii = 0; ii < 4; ++ii) {
                int R = wm + ii * 16 + l15;
                int sc = (quad + kk8) ^ (R & 7);
                af[ii] = *(const shortx8*)&sA[bs][(R * 8 + sc) * 8];
            }
#pragma unroll
            for (int j = 0; j < 4; ++j) {
                int R = wn + j * 16 + l15;
                int sc = (quad + kk8) ^ (R & 7);
                bfr[j] = *(const shortx8*)&sB[bs][(R * 8 + sc) * 8];
            }
#pragma unroll
            for (int ii = 0; ii < 4; ++ii)
#pragma unroll
                for (int j = 0; j < 4; ++j)
                    acc[ii][j] = __builtin_amdgcn_mfma_f32_16x16x32_bf16(af[ii], bfr[j], acc[ii][j], 0, 0, 0);
        }
        __builtin_amdgcn_s_barrier();
        if (i + 2 < T) stage(i + 2, bs);
    }

#pragma unroll
    for (int i = 0; i < 4; ++i) {
        int row = m0 + wm + i * 16 + quad * 4;
#pragma unroll
        for (int j = 0; j < 4; ++j) {
            int col = n0 + wn + j * 16 + l15;
            float bs2 = bias[col];
#pragma unroll
            for (int r = 0; r < 4; ++r) {
                float v = acc[i][j][r] + bs2;
                int rr = row + r;
                if (EPI & 1) v = gelu_fast(v);
                if (EPI & 16) { if (col < E_DIM) v *= 0.18033688f; }  // 0.125*log2e into Q
                if (EPI & 2) v += resid[(size_t)rr * N + col];
                if (EPI & 4) Cf[(size_t)rr * N + col] = v;
                if (EPI & 8) Cb[(size_t)rr * N + col] = f2bf(v);
            }
        }
    }
}

// ---------------- GEMM 128x128 with in-block K-split (for N=1024 GEMMs).
// 16 waves: (mi,ni,kq); each wave owns a 64x64 sub-tile, consumes k-quarter kq
// of each BK=128 step. LDS layout FIX (R14: 4.19M bank conflicts measured):
// the old (R*2+kh) unit interleave gave rows a 256B stride (addr = R*256 +
// kh*128 + sc*16), losing the row-stride-128 property of the conflict-free
// gemm_16w pattern. Now k-halves are separate 16KB planes: unit = kh*128 + R,
// addr = kh*16384 + R*128 + sc*16 — byte-identical structure to gemm_16w.
// Staging: round p stages k-half p of all 128 rows (source addr change only;
// LDS dest stays linear per global_load_lds rules). ----------------
template<int EPI>
__global__ __launch_bounds__(1024) void gemm_ksp(
        const unsigned short* __restrict__ A, const unsigned short* __restrict__ Bw,
        const float* __restrict__ bias, const float* __restrict__ resid,
        float* __restrict__ Cf, unsigned short* __restrict__ Cb,
        int M, int N, int K) {
    __shared__ unsigned short smem[2][2][128 * 128];   // [buf][op] 128 KB total
    int tid = threadIdx.x;
    int wave = tid >> 6, lane = tid & 63;
    int m_idx, n_idx; xcd_remap(m_idx, n_idx);
    int m0 = m_idx * 128, n0 = n_idx * 128;
    int kq = wave & 3, mi = (wave >> 2) & 1, ni = wave >> 3;
    int l15 = lane & 15, quad = lane >> 4;
    int kh = kq >> 1, cb = (kq & 1) * 4;    // k-half plane + chunk base for this wave

    int lu = wave * 8 + (lane >> 3);        // staging row, 0..127 (same both rounds)
    int scg = (lane & 7) ^ (lu & 7);        // pre-swizzled global k-group

    floatx4 acc[4][4];
#pragma unroll
    for (int i = 0; i < 4; ++i)
#pragma unroll
        for (int j = 0; j < 4; ++j) acc[i][j] = (floatx4)0.f;

    auto stage = [&](int kt, int b) {
        // round p stages k-half p (64 wide) of all 128 rows into plane p
#pragma unroll
        for (int p = 0; p < 2; ++p)
            __builtin_amdgcn_global_load_lds(
                (gas_ptr)(A + (size_t)(m0 + lu) * K + kt * 128 + p * 64 + scg * 8),
                (las_ptr)&smem[b][0][(p * 128 + wave * 8) * 64], 16, 0, 0);
#pragma unroll
        for (int p = 0; p < 2; ++p)
            __builtin_amdgcn_global_load_lds(
                (gas_ptr)(Bw + (size_t)(n0 + lu) * K + kt * 128 + p * 64 + scg * 8),
                (las_ptr)&smem[b][1][(p * 128 + wave * 8) * 64], 16, 0, 0);
    };

    int T = K / 128;   // 32 (FC2) or 8 (out-proj)
    stage(0, 0);
    stage(1, 1);
    for (int i = 0; i < T; ++i) {
        if (i + 1 < T) { asm volatile("s_waitcnt vmcnt(4)" ::: "memory"); }
        else           { asm volatile("s_waitcnt vmcnt(0)" ::: "memory"); }
        __builtin_amdgcn_s_barrier();
        int bs = i & 1;
        shortx8 af[4], bfr[4];
#pragma unroll
        for (int ii = 0; ii < 4; ++ii) {
            int R = mi * 64 + ii * 16 + l15;
            int sc = (cb + quad) ^ (R & 7);
            af[ii] = *(const shortx8*)&smem[bs][0][((kh * 128 + R) * 8 + sc) * 8];
        }
#pragma unroll
        for (int j = 0; j < 4; ++j) {
            int R = ni * 64 + j * 16 + l15;
            int sc = (cb + quad) ^ (R & 7);
            bfr[j] = *(const shortx8*)&smem[bs][1][((kh * 128 + R) * 8 + sc) * 8];
        }
#pragma unroll
        for (int ii = 0; ii < 4; ++ii)
#pragma unroll
            for (int j = 0; j < 4; ++j)
                acc[ii][j] = __builtin_amdgcn_mfma_f32_16x16x32_bf16(af[ii], bfr[j], acc[ii][j], 0, 0, 0);
        __builtin_amdgcn_s_barrier();
        if (i + 2 < T) stage(i + 2, bs);
    }

    // ---- cross-wave kq reduction through (reused) staging LDS ----
    float* red = (float*)&smem[0][0][0];    // 32768 floats = 128 KB
    int base = (mi * 2 + ni) * 2;
    auto wracc = [&](int rid) {
#pragma unroll
        for (int i2 = 0; i2 < 4; ++i2)
#pragma unroll
            for (int j2 = 0; j2 < 4; ++j2)
                *(floatx4*)&red[(size_t)rid * 4096 + ((i2 * 4 + j2) * 64 + lane) * 4] = acc[i2][j2];
    };
    auto rdacc = [&](int rid) {
#pragma unroll
        for (int i2 = 0; i2 < 4; ++i2)
#pragma unroll
            for (int j2 = 0; j2 < 4; ++j2) {
                floatx4 v = *(const floatx4*)&red[(size_t)rid * 4096 + ((i2 * 4 + j2) * 64 + lane) * 4];
                acc[i2][j2] += v;
            }
    };
    if (kq >= 2) wracc(base + (kq - 2));
    __syncthreads();
    if (kq < 2) rdacc(base + kq);           // kq0 += kq2 ; kq1 += kq3
    __syncthreads();
    if (kq == 1) wracc(base);
    __syncthreads();
    if (kq == 0) {
        rdacc(base);                        // kq0 += (kq1+kq3)
#pragma unroll
        for (int i = 0; i < 4; ++i) {
            int row = m0 + mi * 64 + i * 16 + quad * 4;
#pragma unroll
            for (int j = 0; j < 4; ++j) {
                int col = n0 + ni * 64 + j * 16 + l15;
                float bs2 = bias[col];
#pragma unroll
                for (int r = 0; r < 4; ++r) {
                    float v = acc[i][j][r] + bs2;
                    int rr = row + r;
                    if (EPI & 1) v = gelu_fast(v);
                    if (EPI & 2) v += resid[(size_t)rr * N + col];
                    if (EPI & 4) Cf[(size_t)rr * N + col] = v;
                    if (EPI & 8) Cb[(size_t)rr * N + col] = f2bf(v);
                }
            }
        }
    }
}

// ---------------- V transpose: qkv[.,2048+h*64+d] -> vT[bh][d][t] ----------------
__global__ __launch_bounds__(256) void vtrans_kernel(const unsigned short* __restrict__ qkv,
                                                     unsigned short* __restrict__ vT) {
    __shared__ unsigned short tile[64 * 72];
    int tid = threadIdx.x;
    int bh = blockIdx.y, b = bh >> 4, h = bh & 15;
    int t0 = blockIdx.x * 64;
    const unsigned short* vsrc = qkv + (size_t)b * SEQ * QKV_N + 2 * E_DIM + h * HD;
#pragma unroll
    for (int p = 0; p < 2; ++p) {
        int idx = p * 256 + tid;
        int row = idx >> 3, col = (idx & 7) * 8;
        *(shortx8*)&tile[row * 72 + col] =
            *(const shortx8*)&vsrc[(size_t)(t0 + row) * QKV_N + col];
    }
    __syncthreads();
    int d = tid >> 2, tch = (tid & 3) * 16;
    unsigned short* dst = vT + (size_t)bh * HD * SEQ + (size_t)d * SEQ + t0 + tch;
    shortx8 a0, a1;
#pragma unroll
    for (int j = 0; j < 8; ++j) a0[j] = (short)tile[(tch + j) * 72 + d];
#pragma unroll
    for (int j = 0; j < 8; ++j) a1[j] = (short)tile[(tch + 8 + j) * 72 + d];
    *(shortx8*)&dst[0] = a0;
    *(shortx8*)&dst[8] = a1;
}

// ---------------- Flash attention (R9 structure, PROVEN best): 64-key tiles,
// paired q-tiles (2-pass), 4 waves, double-buffered K/V staging with prefetch
// under compute. Scores arrive PRE-SCALED (Q carries 0.125*log2e from the QKV
// epilogue). R10-R13 variants all regressed/neutral; do not modify. ----------------
__global__ __launch_bounds__(256) void attn_kernel(
        const unsigned short* __restrict__ qkv, const unsigned short* __restrict__ vT,
        unsigned short* __restrict__ out) {
    __shared__ unsigned short kt[2][64 * 64];
    __shared__ unsigned short vt[2][64 * 64];
    __shared__ unsigned short ps[4][16 * 64];
    int tid = threadIdx.x;
    int wave = tid >> 6, lane = tid & 63, l15 = lane & 15, quad = lane >> 4;
    int bh = blockIdx.y, b = bh >> 4, h = bh & 15;
    const unsigned short* qbase = qkv + (size_t)b * SEQ * QKV_N + h * HD;
    const unsigned short* kbase = qbase + E_DIM;
    const unsigned short* vtb = vT + (size_t)bh * HD * SEQ;

    int srl = lane >> 3;
    int scg = (lane & 7) ^ srl;

    auto stage = [&](int t, int bsel) {
        int s0 = t * 64;
#pragma unroll
        for (int p = 0; p < 2; ++p) {
            int rbase = p * 32 + wave * 8;
            __builtin_amdgcn_global_load_lds(
                (gas_ptr)&kbase[(size_t)(s0 + rbase + srl) * QKV_N + scg * 8],
                (las_ptr)&kt[bsel][rbase * 64], 16, 0, 0);
            __builtin_amdgcn_global_load_lds(
                (gas_ptr)&vtb[(size_t)(rbase + srl) * SEQ + s0 + scg * 8],
                (las_ptr)&vt[bsel][rbase * 64], 16, 0, 0);
        }
    };

    for (int pass = 0; pass < 2; ++pass) {
        int qt = (pass == 0) ? blockIdx.x : (15 - blockIdx.x);
        int q0 = qt * 64;
        int qrow = q0 + wave * 16;

        shortx8 qa0 = *(const shortx8*)&qbase[(size_t)(qrow + l15) * QKV_N + quad * 8];
        shortx8 qa1 = *(const shortx8*)&qbase[(size_t)(qrow + l15) * QKV_N + 32 + quad * 8];

        floatx4 o[4];
        for (int d = 0; d < 4; ++d) o[d] = (floatx4)0.f;
        float mrun[4], lrun[4];
        for (int r = 0; r < 4; ++r) { mrun[r] = -1e30f; lrun[r] = 0.f; }

        int ntile = qt + 1;
        __syncthreads();          // prior pass's buf reads done before re-staging buf0
        stage(0, 0);
        for (int t = 0; t < ntile; ++t) {
            asm volatile("s_waitcnt vmcnt(0)" ::: "memory");   // my stage(t) rows landed
            __builtin_amdgcn_s_barrier();                      // everyone's landed + WAR fence
            if (t + 1 < ntile) stage(t + 1, (t + 1) & 1);      // prefetch under compute
            int bsel = t & 1;
            int s0 = t * 64;

            floatx4 sfr[4];
#pragma unroll
            for (int ct = 0; ct < 4; ++ct) {
                int R = ct * 16 + l15;
                int sc0 = quad ^ (R & 7), sc1 = (4 + quad) ^ (R & 7);
                shortx8 kb0 = *(const shortx8*)&kt[bsel][(R * 8 + sc0) * 8];
                shortx8 kb1 = *(const shortx8*)&kt[bsel][(R * 8 + sc1) * 8];
                floatx4 s4 = (floatx4)0.f;
                s4 = __builtin_amdgcn_mfma_f32_16x16x32_bf16(qa0, kb0, s4, 0, 0, 0);
                s4 = __builtin_amdgcn_mfma_f32_16x16x32_bf16(qa1, kb1, s4, 0, 0, 0);
                sfr[ct] = s4;
            }

            bool masked = (t == ntile - 1);
#pragma unroll
            for (int r = 0; r < 4; ++r) {
                int qg = qrow + quad * 4 + r;
                float sv[4];
                float mx = mrun[r];
#pragma unroll
                for (int ct = 0; ct < 4; ++ct) {
                    float v = sfr[ct][r];               // pre-scaled in QKV epilogue
                    if (masked && (s0 + ct * 16 + l15 > qg)) v = -1e30f;
                    sv[ct] = v;
                    mx = fmaxf(mx, v);
                }
                for (int mm = 8; mm; mm >>= 1) mx = fmaxf(mx, __shfl_xor(mx, mm));
                float alpha = exp2f(mrun[r] - mx);
                mrun[r] = mx;
                float sum = 0.f;
                float pv[4];
#pragma unroll
                for (int ct = 0; ct < 4; ++ct) { pv[ct] = exp2f(sv[ct] - mx); sum += pv[ct]; }
                for (int mm = 8; mm; mm >>= 1) sum += __shfl_xor(sum, mm);
                lrun[r] = lrun[r] * alpha + sum;
#pragma unroll
                for (int d = 0; d < 4; ++d) o[d][r] *= alpha;
                int row = quad * 4 + r;
#pragma unroll
                for (int ct = 0; ct < 4; ++ct) {
                    int g = ct * 2 + (l15 >> 3);
                    int sc = g ^ (row & 7);
                    ps[wave][row * 64 + sc * 8 + (l15 & 7)] = f2bf(pv[ct]);
                }
            }
            shortx8 pa0, pa1;
            {
                int sc0 = quad ^ (l15 & 7), sc1 = (4 + quad) ^ (l15 & 7);
                pa0 = *(const shortx8*)&ps[wave][(l15 * 8 + sc0) * 8];
                pa1 = *(const shortx8*)&ps[wave][(l15 * 8 + sc1) * 8];
            }
#pragma unroll
            for (int d = 0; d < 4; ++d) {
                int R = d * 16 + l15;
                int sc0 = quad ^ (R & 7), sc1 = (4 + quad) ^ (R & 7);
                shortx8 vb0 = *(const shortx8*)&vt[bsel][(R * 8 + sc0) * 8];
                shortx8 vb1 = *(const shortx8*)&vt[bsel][(R * 8 + sc1) * 8];
                o[d] = __builtin_amdgcn_mfma_f32_16x16x32_bf16(pa0, vb0, o[d], 0, 0, 0);
                o[d] = __builtin_amdgcn_mfma_f32_16x16x32_bf16(pa1, vb1, o[d], 0, 0, 0);
            }
        }

#pragma unroll
        for (int r = 0; r < 4; ++r) {
            float inv = 1.0f / lrun[r];
            int m = (b << 10) + qrow + quad * 4 + r;
#pragma unroll
            for (int d = 0; d < 4; ++d)
                out[(size_t)m * E_DIM + h * HD + d * 16 + l15] = f2bf(o[d][r] * inv);
        }
    }
}

// ---------------- launch ----------------
extern "C" void kernel_launch(void* const* d_in, const int* in_sizes, int n_in,
                              void* d_out, int out_size, void* d_ws, size_t ws_size,
                              hipStream_t stream) {
    const float* x     = (const float*)d_in[0];
    const float* ln1_w = (const float*)d_in[1];
    const float* ln1_b = (const float*)d_in[2];
    const float* ln2_w = (const float*)d_in[3];
    const float* ln2_b = (const float*)d_in[4];
    const float* qkv_w = (const float*)d_in[5];
    const float* qkv_b = (const float*)d_in[6];
    const float* out_w = (const float*)d_in[7];
    const float* out_b = (const float*)d_in[8];
    const float* fc1_w = (const float*)d_in[9];
    const float* fc1_b = (const float*)d_in[10];
    const float* fc2_w = (const float*)d_in[11];
    const float* fc2_b = (const float*)d_in[12];

    char* ws = (char*)d_ws;
    size_t off = 0;
    auto alloc = [&](size_t bytes) { char* p = ws + off; off += bytes; return p; };
    unsigned short* wq   = (unsigned short*)alloc((size_t)3 * E_DIM * E_DIM * 2);
    unsigned short* wo   = (unsigned short*)alloc((size_t)E_DIM * E_DIM * 2);
    unsigned short* w1   = (unsigned short*)alloc((size_t)F_DIM * E_DIM * 2);
    unsigned short* w2   = (unsigned short*)alloc((size_t)E_DIM * F_DIM * 2);
    unsigned short* h1   = (unsigned short*)alloc((size_t)MROWS * E_DIM * 2);
    unsigned short* qkvb = (unsigned short*)alloc((size_t)MROWS * QKV_N * 2);
    unsigned short* vT   = (unsigned short*)alloc((size_t)BATCH * NH * HD * SEQ * 2);
    unsigned short* attn = (unsigned short*)alloc((size_t)MROWS * E_DIM * 2);
    float*          x1   = (float*)alloc((size_t)MROWS * E_DIM * 4);
    unsigned short* h2   = (unsigned short*)alloc((size_t)MROWS * E_DIM * 2);
    unsigned short* g    = (unsigned short*)alloc((size_t)MROWS * F_DIM * 2);

    // fused weight conversion (12.58M elems, float4 -> ushort4)
    f2b_all<<<S_TOT / 4 / 256, 256, 0, stream>>>(qkv_w, out_w, fc1_w, fc2_w, wq, wo, w1, w2);

    ln_kernel<<<MROWS, 256, 0, stream>>>(x, ln1_w, ln1_b, h1);
    // QKV: 256x256, 16 waves; EPI 16 pre-scales Q cols by 0.125*log2e
    gemm_16w<8 | 16><<<dim3(QKV_N / 256, MROWS / 256), 1024, 0, stream>>>(
        h1, wq, qkv_b, nullptr, nullptr, qkvb, MROWS, QKV_N, E_DIM);
    vtrans_kernel<<<dim3(SEQ / 64, BATCH * NH), 256, 0, stream>>>(qkvb, vT);
    // attn: R9 proven structure (paired 2-pass, dbuf staging), scale pre-folded
    attn_kernel<<<dim3(8, BATCH * NH), 256, 0, stream>>>(qkvb, vT, attn);
    // out proj + residual(x) -> x1 fp32   (128x128 K-split tiles, 256 blocks, 1/CU)
    gemm_ksp<2 | 4><<<dim3(E_DIM / 128, MROWS / 128), 1024, 0, stream>>>(
        attn, wo, out_b, x, x1, nullptr, MROWS, E_DIM, E_DIM);
    ln_kernel<<<MROWS, 256, 0, stream>>>(x1, ln2_w, ln2_b, h2);
    // FC1: 256x256, 16 waves (grid 16x16 = 256 blocks = 1/CU, 1024 threads)
    gemm_16w<1 | 8><<<dim3(F_DIM / 256, MROWS / 256), 1024, 0, stream>>>(
        h2, w1, fc1_b, nullptr, nullptr, g, MROWS, F_DIM, E_DIM);
    // FC2 + residual(x1) -> d_out fp32   (128x128 K-split tiles, 256 blocks, 1/CU)
    gemm_ksp<2 | 4><<<dim3(E_DIM / 128, MROWS / 128), 1024, 0, stream>>>(
        g, w2, fc2_b, x1, (float*)d_out, nullptr, MROWS, E_DIM, F_DIM);
}